// Round 10
// baseline (556.125 us; speedup 1.0000x reference)
//
#include <hip/hip_runtime.h>
#include <hip/hip_bf16.h>
#include <math.h>

namespace {

constexpr int BATCH = 32;
constexpr int SEQ   = 512;
constexpr int DIN   = 9;
constexpr int EMB   = 256;
constexpr int FF    = 1024;
constexpr int NLAYER= 4;
constexpr int NCLS  = 10;
constexpr int NHEADS= 8;
constexpr int HDIM  = 32;
constexpr int NTOK  = BATCH*SEQ;      // 16384

typedef __attribute__((ext_vector_type(8))) short short8;
typedef __attribute__((ext_vector_type(4))) float floatx4;

#define GLOAD_LDS16(g, l) __builtin_amdgcn_global_load_lds( \
    (const __attribute__((address_space(1))) unsigned*)(g), \
    (__attribute__((address_space(3))) unsigned*)(l), 16, 0, 0)

// counted vmcnt wait: lets the just-issued prefetch loads stay in flight
// across the barrier while guaranteeing the previous tile's loads landed.
#define WAITCNT(N) asm volatile("s_waitcnt vmcnt(" #N ")" ::: "memory")

// ---------------- bf16 MFMA GEMM, 2-phase double-buffered, counted vmcnt ----------------
// C[M,N] = A[M,K] @ W[N,K]^T + bias. 128x128 tile, BK=32, 4 waves (2x2).
// KV=true: N=512 fused k|v projection — block col bn<256 -> C0 (k), else C1 (v).
template<bool RELU, bool KV>
__global__ __launch_bounds__(256)
void gemm_mfma(const __hip_bfloat16* __restrict__ A, int lda,
               const __hip_bfloat16* __restrict__ W,     // [N,K] row-major
               const float* __restrict__ bias,
               __hip_bfloat16* __restrict__ C0,
               __hip_bfloat16* __restrict__ C1,
               int ldc, int K)
{
    __shared__ __hip_bfloat16 As[2*128*32];
    __shared__ __hip_bfloat16 Bs[2*128*32];
    const int bm = blockIdx.y*128, bn = blockIdx.x*128;
    const int tid  = threadIdx.x;
    const int lane = tid & 63;
    const int w    = tid >> 6;
    const int wm   = (w >> 1)*64, wn = (w & 1)*64;

    floatx4 acc[4][4] = {};

    const int srow = w*32 + (lane >> 2);
    const int scol = (lane & 3)*8;
    const __hip_bfloat16* gA0 = A + (size_t)(bm + srow)*lda + scol;
    const __hip_bfloat16* gA1 = A + (size_t)(bm + srow + 16)*lda + scol;
    const __hip_bfloat16* gB0 = W + (size_t)(bn + srow)*K + scol;
    const __hip_bfloat16* gB1 = W + (size_t)(bn + srow + 16)*K + scol;
    const int l0 = (w*2)*512, l1 = (w*2 + 1)*512;

#define GM_STAGE(buf, k0) do { \
    GLOAD_LDS16(gA0 + (k0), As + (buf)*4096 + l0); \
    GLOAD_LDS16(gA1 + (k0), As + (buf)*4096 + l1); \
    GLOAD_LDS16(gB0 + (k0), Bs + (buf)*4096 + l0); \
    GLOAD_LDS16(gB1 + (k0), Bs + (buf)*4096 + l1); } while (0)

    const int arow = wm + (lane & 15);
    const int brow = wn + (lane & 15);
    const int kh   = lane >> 4;
    const int nt   = K >> 5;

    GM_STAGE(0, 0);                                    // 4 loads in flight
    for (int t = 0; t < nt; t++) {
        const int cur = t & 1;
        if (t + 1 < nt) {
            GM_STAGE(cur ^ 1, (t+1)*32);               // +4 loads (8 outstanding)
            WAITCNT(4);                                // wait prev tile only
        } else {
            WAITCNT(0);                                // last tile: drain all
        }
        __builtin_amdgcn_s_barrier();                  // all waves' cur loads landed
        const short8* Ab = (const short8*)(As + cur*4096);
        const short8* Bb = (const short8*)(Bs + cur*4096);
        short8 af[4], bf[4];
        #pragma unroll
        for (int m = 0; m < 4; m++) af[m] = Ab[(arow + m*16)*4 + kh];
        #pragma unroll
        for (int n = 0; n < 4; n++) bf[n] = Bb[(brow + n*16)*4 + kh];
        #pragma unroll
        for (int m = 0; m < 4; m++)
            #pragma unroll
            for (int n = 0; n < 4; n++)
                acc[m][n] = __builtin_amdgcn_mfma_f32_16x16x32_bf16(af[m], bf[n], acc[m][n], 0, 0, 0);
        __builtin_amdgcn_s_barrier();                  // reads of cur done before overwrite
    }
#undef GM_STAGE

    __hip_bfloat16* Cb;
    int cb;
    if (KV && bn >= 256) { Cb = C1; cb = bn - 256; }
    else                 { Cb = C0; cb = bn; }

    const int crow0 = bm + wm + (lane >> 4)*4;
    #pragma unroll
    for (int n = 0; n < 4; n++) {
        const int coln = wn + (lane & 15) + n*16;
        const float bv = bias[bn + coln];
        #pragma unroll
        for (int m = 0; m < 4; m++) {
            #pragma unroll
            for (int r = 0; r < 4; r++) {
                int row = crow0 + m*16 + r;
                float v = acc[m][n][r] + bv;
                if (RELU) v = fmaxf(v, 0.f);
                Cb[(size_t)row*ldc + cb + coln] = __float2bfloat16(v);
            }
        }
    }
}

// ---------------- fused GEMM + bias + residual + LayerNorm, split-K x2, counted vmcnt ----------------
// C[M,256] = A[M,K] @ W[256,K]^T + bias; xnew = LN(xres + C)*g + b.
// BM=32, 256 threads = 4 waves: w&1 = 16-row group, w>>1 = K-half.
__global__ __launch_bounds__(256)
void gemm_ln(const __hip_bfloat16* __restrict__ A, int lda,
             const __hip_bfloat16* __restrict__ W,     // [256,K]
             const float* __restrict__ bias,
             const float* __restrict__ g,
             const float* __restrict__ bb,
             float* __restrict__ xres,                 // in/out fp32 [NTOK,256]
             __hip_bfloat16* __restrict__ xb16,        // out bf16 mirror
             int K)
{
    // [dbuf][ A: 2half x 32r x 32k (2048) | B: 2half x 256r x 32k (16384) ] bf16 = 72 KB
    __shared__ __hip_bfloat16 SM[2][18432];
    const int bm  = blockIdx.x*32;
    const int tid = threadIdx.x;
    const int lane= tid & 63;
    const int w   = tid >> 6;
    const int rgrp= w & 1;
    const int half= w >> 1;
    const int cl  = lane & 15;
    const int rg  = lane >> 4;
    const int Kh  = K >> 1;

    floatx4 acc[16] = {};

    // 36 staging chunks of 1KB: ids 0-3 = A(h=id>>1, rc=id&1); 4-35 = B(h=(id-4)>>4, rc=(id-4)&15)
    const __hip_bfloat16* gsrc[9];
    int loff[9];
    #pragma unroll
    for (int i = 0; i < 9; i++) {
        int id = w*9 + i;
        if (id < 4) {
            int h = id >> 1, rc = id & 1;
            gsrc[i] = A + (size_t)(bm + rc*16 + (lane >> 2))*lda + h*Kh + (lane & 3)*8;
            loff[i] = h*1024 + rc*512;
        } else {
            int idb = id - 4;
            int h = idb >> 4, rc = idb & 15;
            gsrc[i] = W + (size_t)(rc*16 + (lane >> 2))*K + h*Kh + (lane & 3)*8;
            loff[i] = 2048 + h*8192 + rc*512;
        }
    }

#define GL2_STAGE(buf, k0) do { \
    _Pragma("unroll") \
    for (int i = 0; i < 9; i++) GLOAD_LDS16(gsrc[i] + (k0), &SM[buf][loff[i]]); } while (0)

    const int nt = Kh >> 5;
    GL2_STAGE(0, 0);                                   // 9 loads in flight
    const int aidx = half*128 + (rgrp*16 + cl)*4 + rg;
    for (int t = 0; t < nt; t++) {
        const int cur = t & 1;
        if (t + 1 < nt) {
            GL2_STAGE(cur ^ 1, (t+1)*32);              // +9 (18 outstanding)
            WAITCNT(9);                                // wait prev tile only
        } else {
            WAITCNT(0);
        }
        __builtin_amdgcn_s_barrier();
        const short8* Sb = (const short8*)SM[cur];
        short8 af = Sb[aidx];
        #pragma unroll
        for (int n = 0; n < 16; n++) {
            short8 bf = Sb[256 + half*1024 + (n*16 + cl)*4 + rg];
            acc[n] = __builtin_amdgcn_mfma_f32_16x16x32_bf16(af, bf, acc[n], 0, 0, 0);
        }
        __builtin_amdgcn_s_barrier();
    }
#undef GL2_STAGE

    // cross-wave K reduction via LDS (lane-interleaved, conflict-free)
    float* R = (float*)SM;
    if (half == 1) {
        #pragma unroll
        for (int n = 0; n < 16; n++)
            #pragma unroll
            for (int r = 0; r < 4; r++)
                R[rgrp*4096 + (n*4 + r)*64 + lane] = acc[n][r];
    }
    __syncthreads();
    if (half == 0) {
        #pragma unroll
        for (int n = 0; n < 16; n++)
            #pragma unroll
            for (int r = 0; r < 4; r++)
                acc[n][r] += R[rgrp*4096 + (n*4 + r)*64 + lane];

        float bv[16], gv[16], bbv[16];
        #pragma unroll
        for (int n = 0; n < 16; n++) {
            const int c = n*16 + cl;
            bv[n] = bias[c]; gv[n] = g[c]; bbv[n] = bb[c];
        }
        #pragma unroll
        for (int r = 0; r < 4; r++) {
            const int row = bm + rgrp*16 + rg*4 + r;
            float* xr = xres + (size_t)row*EMB;
            __hip_bfloat16* xbr = xb16 + (size_t)row*EMB;
            float vals[16];
            float S = 0.f, Q = 0.f;
            #pragma unroll
            for (int n = 0; n < 16; n++) {
                float v = acc[n][r] + bv[n] + xr[n*16 + cl];
                vals[n] = v; S += v; Q += v*v;
            }
            #pragma unroll
            for (int o = 1; o < 16; o <<= 1) { S += __shfl_xor(S, o); Q += __shfl_xor(Q, o); }
            const float mean = S * (1.f/EMB);
            const float var  = Q * (1.f/EMB) - mean*mean;
            const float rstd = 1.f / sqrtf(var + 1e-5f);
            #pragma unroll
            for (int n = 0; n < 16; n++) {
                float v = (vals[n] - mean)*rstd*gv[n] + bbv[n];
                xr [n*16 + cl] = v;
                xbr[n*16 + cl] = __float2bfloat16(v);
            }
        }
    }
}

// ---------------- fused fp32 -> bf16 weight conversion (all 4 arrays, 1 launch) ----------------
// segments (in 1024-elem blocks): Wqkv 768 | Wo 256 | W1 1024 | W2 1024
__global__ void f2b_all(const float* __restrict__ s0, const float* __restrict__ s1,
                        const float* __restrict__ s2, const float* __restrict__ s3,
                        __hip_bfloat16* __restrict__ d0, __hip_bfloat16* __restrict__ d1,
                        __hip_bfloat16* __restrict__ d2, __hip_bfloat16* __restrict__ d3)
{
    int blk = blockIdx.x;
    const float* s; __hip_bfloat16* d; int base;
    if      (blk <  768) { s = s0; d = d0; base = blk; }
    else if (blk < 1024) { s = s1; d = d1; base = blk - 768; }
    else if (blk < 2048) { s = s2; d = d2; base = blk - 1024; }
    else                 { s = s3; d = d3; base = blk - 2048; }
    int i = (base*256 + threadIdx.x)*4;
    float4 v = *(const float4*)(s + i);
    __hip_bfloat16 tmp[4];
    tmp[0] = __float2bfloat16(v.x); tmp[1] = __float2bfloat16(v.y);
    tmp[2] = __float2bfloat16(v.z); tmp[3] = __float2bfloat16(v.w);
    *(ushort4*)(d + i) = *(const ushort4*)tmp;
}

// ---------------- embed + scale + pos-enc; writes fp32 + bf16 mirrors ----------------
__global__ void embed_kernel(const float* __restrict__ src,
                             const float* __restrict__ emb_W,
                             const float* __restrict__ emb_b,
                             float* __restrict__ x,
                             __hip_bfloat16* __restrict__ xb)
{
    int row = blockIdx.x;
    int e = threadIdx.x;
    int s = row % SEQ;
    const float* sr = src + (size_t)row*DIN;
    float acc = emb_b[e];
    #pragma unroll
    for (int d = 0; d < DIN; d++) acc += sr[d]*emb_W[e*DIN + d];
    acc *= 16.0f;                    // sqrt(EMB)
    int i2 = e & ~1;
    float div = expf(-(float)i2 * (9.210340371976184f / (float)EMB));
    float ang = (float)s * div;
    float pe = (e & 1) ? cosf(ang) : sinf(ang);
    float v = acc + pe;
    x [(size_t)row*EMB + e] = v;
    xb[(size_t)row*EMB + e] = __float2bfloat16(v);
}

// ---------------- per-(b,h) last-row attention (contiguous k/v buffers) ----------------
__global__ __launch_bounds__(512)
void attn_last_head(const float* __restrict__ x,          // [NTOK, EMB] fp32
                    const float* __restrict__ Wq,         // [EMB, EMB] (q rows of Wqkv[l])
                    const float* __restrict__ bq,
                    const __hip_bfloat16* __restrict__ kbuf, // [B*S,256]
                    __hip_bfloat16* __restrict__ vbuf,       // [B*S,256]
                    float* __restrict__ amh)              // [B*H, SEQ] for this layer
{
    const int h = blockIdx.x, b = blockIdx.y;
    const int t = threadIdx.x;                 // 0..511
    __shared__ float xlast[EMB];
    __shared__ float qpart[HDIM][17];
    __shared__ float qh[HDIM];
    __shared__ float sc[SEQ];
    __shared__ float red1[8], red2[8];
    __shared__ float opart[16][HDIM];

    if (t < EMB) xlast[t] = x[((size_t)b*SEQ + SEQ-1)*EMB + t];
    __syncthreads();

    {
        int d = t & 31, c = t >> 5;            // c in 0..15
        const float* wr = Wq + (size_t)(h*HDIM + d)*EMB + c*16;
        float p = 0.f;
        #pragma unroll
        for (int j = 0; j < 16; j++) p += xlast[c*16 + j]*wr[j];
        qpart[d][c] = p;
    }
    __syncthreads();
    if (t < HDIM) {
        float qv = bq[h*HDIM + t];
        #pragma unroll
        for (int c = 0; c < 16; c++) qv += qpart[t][c];
        qh[t] = qv;
    }
    __syncthreads();

    // score for key t (this head only)
    {
        const __hip_bfloat16* krow = kbuf + ((size_t)b*SEQ + t)*EMB + h*HDIM;
        float s = 0.f;
        #pragma unroll
        for (int vv = 0; vv < 4; vv++) {
            short8 kk = *(const short8*)(krow + vv*8);
            #pragma unroll
            for (int j = 0; j < 8; j++)
                s += qh[vv*8 + j]*__bfloat162float(((const __hip_bfloat16*)&kk)[j]);
        }
        s *= 0.17677669529663687f;
        if (t == SEQ-1) s += -1e9f;
        sc[t] = s;
    }
    __syncthreads();

    // block softmax over 512 scores (8 waves)
    {
        int wv = t >> 6, lane = t & 63;
        float m = sc[t];
        #pragma unroll
        for (int o = 32; o; o >>= 1) m = fmaxf(m, __shfl_xor(m, o));
        if (lane == 0) red1[wv] = m;
        __syncthreads();
        m = red1[0];
        #pragma unroll
        for (int i = 1; i < 8; i++) m = fmaxf(m, red1[i]);
        float e = expf(sc[t] - m);
        float s = e;
        #pragma unroll
        for (int o = 32; o; o >>= 1) s += __shfl_xor(s, o);
        if (lane == 0) red2[wv] = s;
        __syncthreads();
        float tot = red2[0]+red2[1]+red2[2]+red2[3]+red2[4]+red2[5]+red2[6]+red2[7];
        float a = e / tot;
        sc[t] = a;
        amh[((size_t)b*NHEADS + h)*SEQ + t] = a;
    }
    __syncthreads();

    // o_last for this head's 32 dims: 16-way k-partition
    {
        int e = t & 31, part = t >> 5;
        float o = 0.f;
        const __hip_bfloat16* vc = vbuf + (size_t)b*SEQ*EMB + h*HDIM + e;
        for (int k = part*32; k < part*32 + 32; k++)
            o += sc[k]*__bfloat162float(vc[(size_t)k*EMB]);
        opart[part][e] = o;
    }
    __syncthreads();
    if (t < HDIM) {
        float o = 0.f;
        #pragma unroll
        for (int p = 0; p < 16; p++) o += opart[p][t];
        vbuf[((size_t)b*SEQ + SEQ-1)*EMB + h*HDIM + t] = __float2bfloat16(o);
    }
}

// ---------------- write full attns output [L,B,S,S]; head-avg fused for last rows ----------------
__global__ void write_attns(float* __restrict__ attns, const float* __restrict__ amh_all)
{
    constexpr int PER_ROW = SEQ/4;
    size_t tid = (size_t)blockIdx.x*blockDim.x + threadIdx.x;
    size_t row = tid / PER_ROW;
    int c4 = (int)(tid % PER_ROW);
    int q = (int)(row % SEQ);
    float4 v = make_float4(0.f,0.f,0.f,0.f);
    if (q == SEQ-1) {
        size_t lb = row / SEQ;
        const float* base = amh_all + lb*NHEADS*SEQ + c4*4;
        float x0=0.f, x1=0.f, x2=0.f, x3=0.f;
        #pragma unroll
        for (int h = 0; h < NHEADS; h++) {
            const float* r = base + (size_t)h*SEQ;
            x0 += r[0]; x1 += r[1]; x2 += r[2]; x3 += r[3];
        }
        v = make_float4(x0*0.125f, x1*0.125f, x2*0.125f, x3*0.125f);
    } else if ((q >> 2) == c4) {
        ((float*)&v)[q & 3] = 1.f;
    }
    ((float4*)attns)[tid] = v;
}

// ---------------- partial relu-sum over sequence chunks ----------------
__global__ void reduce_relu_part(const float* __restrict__ x, float* __restrict__ rp)
{
    int b = blockIdx.x, ch = blockIdx.y, e = threadIdx.x;
    const float* xb = x + ((size_t)b*SEQ + ch*(SEQ/8))*EMB;
    float s = 0.f;
    for (int i = 0; i < SEQ/8; i++) s += fmaxf(xb[(size_t)i*EMB + e], 0.f);
    rp[(b*8 + ch)*EMB + e] = s;
}

// ---------------- parallel decode + log_softmax: one block per batch row ----------------
__global__ __launch_bounds__(256)
void decode_out2(const float* __restrict__ rp, const float* __restrict__ dec_W,
                 float* __restrict__ out)
{
    int b = blockIdx.x, t = threadIdx.x;
    float r = 0.f;
    #pragma unroll
    for (int ch = 0; ch < 8; ch++) r += rp[(b*8 + ch)*EMB + t];
    float part[NCLS];
    #pragma unroll
    for (int c = 0; c < NCLS; c++) part[c] = r * dec_W[c*EMB + t];
    #pragma unroll
    for (int o = 32; o; o >>= 1)
        #pragma unroll
        for (int c = 0; c < NCLS; c++) part[c] += __shfl_xor(part[c], o);
    __shared__ float red[4][NCLS];
    int wv = t >> 6, lane = t & 63;
    if (lane == 0)
        #pragma unroll
        for (int c = 0; c < NCLS; c++) red[wv][c] = part[c];
    __syncthreads();
    if (t == 0) {
        float lg[NCLS];
        float m = -1e30f;
        #pragma unroll
        for (int c = 0; c < NCLS; c++) {
            lg[c] = (red[0][c]+red[1][c]+red[2][c]+red[3][c]) * (1.f/(float)SEQ);
            m = fmaxf(m, lg[c]);
        }
        float s = 0.f;
        #pragma unroll
        for (int c = 0; c < NCLS; c++) s += expf(lg[c] - m);
        float ls = logf(s);
        #pragma unroll
        for (int c = 0; c < NCLS; c++) out[b*NCLS + c] = lg[c] - m - ls;
    }
}

} // namespace

extern "C" void kernel_launch(void* const* d_in, const int* in_sizes, int n_in,
                              void* d_out, int out_size, void* d_ws, size_t ws_size,
                              hipStream_t stream)
{
    const float* src   = (const float*)d_in[0];
    const float* emb_W = (const float*)d_in[1];
    const float* emb_b = (const float*)d_in[2];
    const float* Wqkv  = (const float*)d_in[3];
    const float* bqkv  = (const float*)d_in[4];
    const float* Wo    = (const float*)d_in[5];
    const float* bo    = (const float*)d_in[6];
    const float* ln1_g = (const float*)d_in[7];
    const float* ln1_b = (const float*)d_in[8];
    const float* ln2_g = (const float*)d_in[9];
    const float* ln2_b = (const float*)d_in[10];
    const float* W1    = (const float*)d_in[11];
    const float* b1    = (const float*)d_in[12];
    const float* W2    = (const float*)d_in[13];
    const float* b2    = (const float*)d_in[14];
    const float* dec_W = (const float*)d_in[15];

    float* out   = (float*)d_out;               // [32,10]
    float* attns = out + BATCH*NCLS;            // [4,32,512,512]

    // workspace layout (~84 MB), no aliasing
    char* ws = (char*)d_ws;
    float*          xbuf = (float*)ws;              ws += (size_t)NTOK*EMB*4;     // 16.78 MB
    __hip_bfloat16* xb16 = (__hip_bfloat16*)ws;     ws += (size_t)NTOK*EMB*2;     //  8.39 MB
    __hip_bfloat16* kbuf = (__hip_bfloat16*)ws;     ws += (size_t)NTOK*EMB*2;     //  8.39 MB
    __hip_bfloat16* vbuf = (__hip_bfloat16*)ws;     ws += (size_t)NTOK*EMB*2;     //  8.39 MB
    __hip_bfloat16* hbuf = (__hip_bfloat16*)ws;     ws += (size_t)NTOK*FF*2;      // 33.55 MB
    __hip_bfloat16* wq16 = (__hip_bfloat16*)ws;     ws += (size_t)NLAYER*3*EMB*EMB*2;
    __hip_bfloat16* wo16 = (__hip_bfloat16*)ws;     ws += (size_t)NLAYER*EMB*EMB*2;
    __hip_bfloat16* w116 = (__hip_bfloat16*)ws;     ws += (size_t)NLAYER*FF*EMB*2;
    __hip_bfloat16* w216 = (__hip_bfloat16*)ws;     ws += (size_t)NLAYER*EMB*FF*2;
    float*          amall= (float*)ws;              ws += (size_t)NLAYER*BATCH*NHEADS*SEQ*4; // 2.1 MB
    float*          rpart= (float*)ws;              ws += BATCH*8*EMB*4;

    // weight conversion fp32 -> bf16 (single launch)
    f2b_all<<<3072, 256, 0, stream>>>(Wqkv, Wo, W1, W2, wq16, wo16, w116, w216);

    embed_kernel<<<NTOK, EMB, 0, stream>>>(src, emb_W, emb_b, xbuf, xb16);

    for (int l = 0; l < NLAYER; l++) {
        const __hip_bfloat16* wql = wq16 + (size_t)l*3*EMB*EMB;
        const float* bql = bqkv + (size_t)l*3*EMB;

        // fused k|v projection: N=512 over W rows [E..3E)
        gemm_mfma<false, true><<<dim3(512/128, NTOK/128), 256, 0, stream>>>(
            xb16, EMB, wql + (size_t)EMB*EMB, bql + EMB, kbuf, vbuf, EMB, EMB);

        // fused per-(b,h): q GEMV + scores + softmax + per-head row + o_last
        attn_last_head<<<dim3(NHEADS, BATCH), 512, 0, stream>>>(
            xbuf, Wqkv + (size_t)l*3*EMB*EMB, bqkv + (size_t)l*3*EMB,
            kbuf, vbuf, amall + (size_t)l*BATCH*NHEADS*SEQ);

        // Wo GEMM + bias + residual + LN1 (writes xbuf/xb16)
        gemm_ln<<<NTOK/32, 256, 0, stream>>>(
            vbuf, EMB, wo16 + (size_t)l*EMB*EMB, bo + (size_t)l*EMB,
            ln1_g + l*EMB, ln1_b + l*EMB, xbuf, xb16, EMB);

        // FFN1 (relu, bf16 out)
        gemm_mfma<true, false><<<dim3(FF/128, NTOK/128), 256, 0, stream>>>(
            xb16, EMB, w116 + (size_t)l*FF*EMB, b1 + (size_t)l*FF, hbuf, nullptr, FF, EMB);

        // FFN2 GEMM + bias + residual + LN2
        gemm_ln<<<NTOK/32, 256, 0, stream>>>(
            hbuf, FF, w216 + (size_t)l*EMB*FF, b2 + (size_t)l*EMB,
            ln2_g + l*EMB, ln2_b + l*EMB, xbuf, xb16, FF);
    }

    {
        size_t total_f4 = (size_t)NLAYER*BATCH*SEQ*(SEQ/4);
        int blocks = (int)((total_f4 + 255)/256);
        write_attns<<<blocks, 256, 0, stream>>>(attns, amall);
    }

    reduce_relu_part<<<dim3(BATCH, 8), EMB, 0, stream>>>(xbuf, rpart);
    decode_out2<<<BATCH, 256, 0, stream>>>(rpart, dec_W, out);
}

// Round 11
// 546.682 us; speedup vs baseline: 1.0173x; 1.0173x over previous
//
#include <hip/hip_runtime.h>
#include <hip/hip_bf16.h>
#include <math.h>

namespace {

constexpr int BATCH = 32;
constexpr int SEQ   = 512;
constexpr int DIN   = 9;
constexpr int EMB   = 256;
constexpr int FF    = 1024;
constexpr int NLAYER= 4;
constexpr int NCLS  = 10;
constexpr int NHEADS= 8;
constexpr int HDIM  = 32;
constexpr int NTOK  = BATCH*SEQ;      // 16384

typedef __attribute__((ext_vector_type(8))) short short8;
typedef __attribute__((ext_vector_type(4))) float floatx4;

#define GLOAD_LDS16(g, l) __builtin_amdgcn_global_load_lds( \
    (const __attribute__((address_space(1))) unsigned*)(g), \
    (__attribute__((address_space(3))) unsigned*)(l), 16, 0, 0)

#define WAITCNT(N) asm volatile("s_waitcnt vmcnt(" #N ")" ::: "memory")

// ---------------- bf16 MFMA GEMM, 2-phase double-buffered, counted vmcnt ----------------
// C[M,N] = A[M,K] @ W[N,K]^T + bias. 128x128 tile, BK=32, 4 waves (2x2).
// KV=true: N=512 fused k|v projection — block col bn<256 -> C0 (k), else C1 (v).
template<bool RELU, bool KV>
__global__ __launch_bounds__(256)
void gemm_mfma(const __hip_bfloat16* __restrict__ A, int lda,
               const __hip_bfloat16* __restrict__ W,     // [N,K] row-major
               const float* __restrict__ bias,
               __hip_bfloat16* __restrict__ C0,
               __hip_bfloat16* __restrict__ C1,
               int ldc, int K)
{
    __shared__ __hip_bfloat16 As[2*128*32];
    __shared__ __hip_bfloat16 Bs[2*128*32];
    const int bm = blockIdx.y*128, bn = blockIdx.x*128;
    const int tid  = threadIdx.x;
    const int lane = tid & 63;
    const int w    = tid >> 6;
    const int wm   = (w >> 1)*64, wn = (w & 1)*64;

    floatx4 acc[4][4] = {};

    const int srow = w*32 + (lane >> 2);
    const int scol = (lane & 3)*8;
    const __hip_bfloat16* gA0 = A + (size_t)(bm + srow)*lda + scol;
    const __hip_bfloat16* gA1 = A + (size_t)(bm + srow + 16)*lda + scol;
    const __hip_bfloat16* gB0 = W + (size_t)(bn + srow)*K + scol;
    const __hip_bfloat16* gB1 = W + (size_t)(bn + srow + 16)*K + scol;
    const int l0 = (w*2)*512, l1 = (w*2 + 1)*512;

#define GM_STAGE(buf, k0) do { \
    GLOAD_LDS16(gA0 + (k0), As + (buf)*4096 + l0); \
    GLOAD_LDS16(gA1 + (k0), As + (buf)*4096 + l1); \
    GLOAD_LDS16(gB0 + (k0), Bs + (buf)*4096 + l0); \
    GLOAD_LDS16(gB1 + (k0), Bs + (buf)*4096 + l1); } while (0)

    const int arow = wm + (lane & 15);
    const int brow = wn + (lane & 15);
    const int kh   = lane >> 4;
    const int nt   = K >> 5;

    GM_STAGE(0, 0);
    for (int t = 0; t < nt; t++) {
        const int cur = t & 1;
        if (t + 1 < nt) {
            GM_STAGE(cur ^ 1, (t+1)*32);
            WAITCNT(4);
        } else {
            WAITCNT(0);
        }
        __builtin_amdgcn_s_barrier();
        const short8* Ab = (const short8*)(As + cur*4096);
        const short8* Bb = (const short8*)(Bs + cur*4096);
        short8 af[4], bf[4];
        #pragma unroll
        for (int m = 0; m < 4; m++) af[m] = Ab[(arow + m*16)*4 + kh];
        #pragma unroll
        for (int n = 0; n < 4; n++) bf[n] = Bb[(brow + n*16)*4 + kh];
        #pragma unroll
        for (int m = 0; m < 4; m++)
            #pragma unroll
            for (int n = 0; n < 4; n++)
                acc[m][n] = __builtin_amdgcn_mfma_f32_16x16x32_bf16(af[m], bf[n], acc[m][n], 0, 0, 0);
        __builtin_amdgcn_s_barrier();
    }
#undef GM_STAGE

    __hip_bfloat16* Cb;
    int cb;
    if (KV && bn >= 256) { Cb = C1; cb = bn - 256; }
    else                 { Cb = C0; cb = bn; }

    const int crow0 = bm + wm + (lane >> 4)*4;
    #pragma unroll
    for (int n = 0; n < 4; n++) {
        const int coln = wn + (lane & 15) + n*16;
        const float bv = bias[bn + coln];
        #pragma unroll
        for (int m = 0; m < 4; m++) {
            #pragma unroll
            for (int r = 0; r < 4; r++) {
                int row = crow0 + m*16 + r;
                float v = acc[m][n][r] + bv;
                if (RELU) v = fmaxf(v, 0.f);
                Cb[(size_t)row*ldc + cb + coln] = __float2bfloat16(v);
            }
        }
    }
}

// ---------------- fused GEMM + bias + residual + LayerNorm, split-K x2 (all-bf16 x) ----------------
// C[M,256] = A[M,K] @ W[256,K]^T + bias; xnew = LN(x_old + C)*g + b, x in bf16.
// BM=32, 256 threads = 4 waves: w&1 = 16-row group, w>>1 = K-half.
__global__ __launch_bounds__(256)
void gemm_ln(const __hip_bfloat16* __restrict__ A, int lda,
             const __hip_bfloat16* __restrict__ W,     // [256,K]
             const float* __restrict__ bias,
             const float* __restrict__ g,
             const float* __restrict__ bb,
             __hip_bfloat16* __restrict__ xb16,        // in/out bf16 [NTOK,256]
             int K)
{
    // [dbuf][ A: 2half x 32r x 32k (2048) | B: 2half x 256r x 32k (16384) ] bf16 = 72 KB
    __shared__ __hip_bfloat16 SM[2][18432];
    const int bm  = blockIdx.x*32;
    const int tid = threadIdx.x;
    const int lane= tid & 63;
    const int w   = tid >> 6;
    const int rgrp= w & 1;
    const int half= w >> 1;
    const int cl  = lane & 15;
    const int rg  = lane >> 4;
    const int Kh  = K >> 1;

    floatx4 acc[16] = {};

    const __hip_bfloat16* gsrc[9];
    int loff[9];
    #pragma unroll
    for (int i = 0; i < 9; i++) {
        int id = w*9 + i;
        if (id < 4) {
            int h = id >> 1, rc = id & 1;
            gsrc[i] = A + (size_t)(bm + rc*16 + (lane >> 2))*lda + h*Kh + (lane & 3)*8;
            loff[i] = h*1024 + rc*512;
        } else {
            int idb = id - 4;
            int h = idb >> 4, rc = idb & 15;
            gsrc[i] = W + (size_t)(rc*16 + (lane >> 2))*K + h*Kh + (lane & 3)*8;
            loff[i] = 2048 + h*8192 + rc*512;
        }
    }

#define GL2_STAGE(buf, k0) do { \
    _Pragma("unroll") \
    for (int i = 0; i < 9; i++) GLOAD_LDS16(gsrc[i] + (k0), &SM[buf][loff[i]]); } while (0)

    const int nt = Kh >> 5;
    GL2_STAGE(0, 0);
    const int aidx = half*128 + (rgrp*16 + cl)*4 + rg;
    for (int t = 0; t < nt; t++) {
        const int cur = t & 1;
        if (t + 1 < nt) {
            GL2_STAGE(cur ^ 1, (t+1)*32);
            WAITCNT(9);
        } else {
            WAITCNT(0);
        }
        __builtin_amdgcn_s_barrier();
        const short8* Sb = (const short8*)SM[cur];
        short8 af = Sb[aidx];
        #pragma unroll
        for (int n = 0; n < 16; n++) {
            short8 bf = Sb[256 + half*1024 + (n*16 + cl)*4 + rg];
            acc[n] = __builtin_amdgcn_mfma_f32_16x16x32_bf16(af, bf, acc[n], 0, 0, 0);
        }
        __builtin_amdgcn_s_barrier();
    }
#undef GL2_STAGE

    // cross-wave K reduction via LDS (lane-interleaved, conflict-free)
    float* R = (float*)SM;
    if (half == 1) {
        #pragma unroll
        for (int n = 0; n < 16; n++)
            #pragma unroll
            for (int r = 0; r < 4; r++)
                R[rgrp*4096 + (n*4 + r)*64 + lane] = acc[n][r];
    }
    __syncthreads();
    if (half == 0) {
        #pragma unroll
        for (int n = 0; n < 16; n++)
            #pragma unroll
            for (int r = 0; r < 4; r++)
                acc[n][r] += R[rgrp*4096 + (n*4 + r)*64 + lane];

        float bv[16], gv[16], bbv[16];
        #pragma unroll
        for (int n = 0; n < 16; n++) {
            const int c = n*16 + cl;
            bv[n] = bias[c]; gv[n] = g[c]; bbv[n] = bb[c];
        }
        #pragma unroll
        for (int r = 0; r < 4; r++) {
            const int row = bm + rgrp*16 + rg*4 + r;
            __hip_bfloat16* xbr = xb16 + (size_t)row*EMB;
            float vals[16];
            float S = 0.f, Q = 0.f;
            #pragma unroll
            for (int n = 0; n < 16; n++) {
                float v = acc[n][r] + bv[n] + __bfloat162float(xbr[n*16 + cl]);
                vals[n] = v; S += v; Q += v*v;
            }
            #pragma unroll
            for (int o = 1; o < 16; o <<= 1) { S += __shfl_xor(S, o); Q += __shfl_xor(Q, o); }
            const float mean = S * (1.f/EMB);
            const float var  = Q * (1.f/EMB) - mean*mean;
            const float rstd = 1.f / sqrtf(var + 1e-5f);
            #pragma unroll
            for (int n = 0; n < 16; n++) {
                float v = (vals[n] - mean)*rstd*gv[n] + bbv[n];
                xbr[n*16 + cl] = __float2bfloat16(v);
            }
        }
    }
}

// ---------------- fused fp32 -> bf16 weight conversion (all 4 arrays, 1 launch) ----------------
__global__ void f2b_all(const float* __restrict__ s0, const float* __restrict__ s1,
                        const float* __restrict__ s2, const float* __restrict__ s3,
                        __hip_bfloat16* __restrict__ d0, __hip_bfloat16* __restrict__ d1,
                        __hip_bfloat16* __restrict__ d2, __hip_bfloat16* __restrict__ d3)
{
    int blk = blockIdx.x;
    const float* s; __hip_bfloat16* d; int base;
    if      (blk <  768) { s = s0; d = d0; base = blk; }
    else if (blk < 1024) { s = s1; d = d1; base = blk - 768; }
    else if (blk < 2048) { s = s2; d = d2; base = blk - 1024; }
    else                 { s = s3; d = d3; base = blk - 2048; }
    int i = (base*256 + threadIdx.x)*4;
    float4 v = *(const float4*)(s + i);
    __hip_bfloat16 tmp[4];
    tmp[0] = __float2bfloat16(v.x); tmp[1] = __float2bfloat16(v.y);
    tmp[2] = __float2bfloat16(v.z); tmp[3] = __float2bfloat16(v.w);
    *(ushort4*)(d + i) = *(const ushort4*)tmp;
}

// ---------------- embed + scale + pos-enc; writes bf16 x ----------------
__global__ void embed_kernel(const float* __restrict__ src,
                             const float* __restrict__ emb_W,
                             const float* __restrict__ emb_b,
                             __hip_bfloat16* __restrict__ xb)
{
    int row = blockIdx.x;
    int e = threadIdx.x;
    int s = row % SEQ;
    const float* sr = src + (size_t)row*DIN;
    float acc = emb_b[e];
    #pragma unroll
    for (int d = 0; d < DIN; d++) acc += sr[d]*emb_W[e*DIN + d];
    acc *= 16.0f;                    // sqrt(EMB)
    int i2 = e & ~1;
    float div = expf(-(float)i2 * (9.210340371976184f / (float)EMB));
    float ang = (float)s * div;
    float pe = (e & 1) ? cosf(ang) : sinf(ang);
    xb[(size_t)row*EMB + e] = __float2bfloat16(acc + pe);
}

// ---------------- per-(b,h) last-row attention (bf16 x, bf16 Wq) ----------------
__global__ __launch_bounds__(512)
void attn_last_head(const __hip_bfloat16* __restrict__ xb,   // [NTOK, EMB] bf16
                    const __hip_bfloat16* __restrict__ Wq,   // [EMB, EMB] bf16 (q rows)
                    const float* __restrict__ bq,
                    const __hip_bfloat16* __restrict__ kbuf, // [B*S,256]
                    __hip_bfloat16* __restrict__ vbuf,       // [B*S,256]
                    float* __restrict__ amh)                 // [B*H, SEQ] for this layer
{
    const int h = blockIdx.x, b = blockIdx.y;
    const int t = threadIdx.x;                 // 0..511
    __shared__ float xlast[EMB];
    __shared__ float qpart[HDIM][17];
    __shared__ float qh[HDIM];
    __shared__ float sc[SEQ];
    __shared__ float red1[8], red2[8];
    __shared__ float opart[16][HDIM];

    if (t < EMB) xlast[t] = __bfloat162float(xb[((size_t)b*SEQ + SEQ-1)*EMB + t]);
    __syncthreads();

    {
        int d = t & 31, c = t >> 5;            // c in 0..15
        const __hip_bfloat16* wr = Wq + (size_t)(h*HDIM + d)*EMB + c*16;
        short8 w0 = *(const short8*)(wr);
        short8 w1 = *(const short8*)(wr + 8);
        float p = 0.f;
        #pragma unroll
        for (int j = 0; j < 8; j++)
            p += xlast[c*16 + j]*__bfloat162float(((const __hip_bfloat16*)&w0)[j]);
        #pragma unroll
        for (int j = 0; j < 8; j++)
            p += xlast[c*16 + 8 + j]*__bfloat162float(((const __hip_bfloat16*)&w1)[j]);
        qpart[d][c] = p;
    }
    __syncthreads();
    if (t < HDIM) {
        float qv = bq[h*HDIM + t];
        #pragma unroll
        for (int c = 0; c < 16; c++) qv += qpart[t][c];
        qh[t] = qv;
    }
    __syncthreads();

    // score for key t (this head only)
    {
        const __hip_bfloat16* krow = kbuf + ((size_t)b*SEQ + t)*EMB + h*HDIM;
        float s = 0.f;
        #pragma unroll
        for (int vv = 0; vv < 4; vv++) {
            short8 kk = *(const short8*)(krow + vv*8);
            #pragma unroll
            for (int j = 0; j < 8; j++)
                s += qh[vv*8 + j]*__bfloat162float(((const __hip_bfloat16*)&kk)[j]);
        }
        s *= 0.17677669529663687f;
        if (t == SEQ-1) s += -1e9f;
        sc[t] = s;
    }
    __syncthreads();

    // block softmax over 512 scores (8 waves)
    {
        int wv = t >> 6, lane = t & 63;
        float m = sc[t];
        #pragma unroll
        for (int o = 32; o; o >>= 1) m = fmaxf(m, __shfl_xor(m, o));
        if (lane == 0) red1[wv] = m;
        __syncthreads();
        m = red1[0];
        #pragma unroll
        for (int i = 1; i < 8; i++) m = fmaxf(m, red1[i]);
        float e = expf(sc[t] - m);
        float s = e;
        #pragma unroll
        for (int o = 32; o; o >>= 1) s += __shfl_xor(s, o);
        if (lane == 0) red2[wv] = s;
        __syncthreads();
        float tot = red2[0]+red2[1]+red2[2]+red2[3]+red2[4]+red2[5]+red2[6]+red2[7];
        float a = e / tot;
        sc[t] = a;
        amh[((size_t)b*NHEADS + h)*SEQ + t] = a;
    }
    __syncthreads();

    // o_last for this head's 32 dims: 16-way k-partition
    {
        int e = t & 31, part = t >> 5;
        float o = 0.f;
        const __hip_bfloat16* vc = vbuf + (size_t)b*SEQ*EMB + h*HDIM + e;
        for (int k = part*32; k < part*32 + 32; k++)
            o += sc[k]*__bfloat162float(vc[(size_t)k*EMB]);
        opart[part][e] = o;
    }
    __syncthreads();
    if (t < HDIM) {
        float o = 0.f;
        #pragma unroll
        for (int p = 0; p < 16; p++) o += opart[p][t];
        vbuf[((size_t)b*SEQ + SEQ-1)*EMB + h*HDIM + t] = __float2bfloat16(o);
    }
}

// ---------------- write full attns output [L,B,S,S]; head-avg fused for last rows ----------------
__global__ void write_attns(float* __restrict__ attns, const float* __restrict__ amh_all)
{
    constexpr int PER_ROW = SEQ/4;
    size_t tid = (size_t)blockIdx.x*blockDim.x + threadIdx.x;
    size_t row = tid / PER_ROW;
    int c4 = (int)(tid % PER_ROW);
    int q = (int)(row % SEQ);
    float4 v = make_float4(0.f,0.f,0.f,0.f);
    if (q == SEQ-1) {
        size_t lb = row / SEQ;
        const float* base = amh_all + lb*NHEADS*SEQ + c4*4;
        float x0=0.f, x1=0.f, x2=0.f, x3=0.f;
        #pragma unroll
        for (int h = 0; h < NHEADS; h++) {
            const float* r = base + (size_t)h*SEQ;
            x0 += r[0]; x1 += r[1]; x2 += r[2]; x3 += r[3];
        }
        v = make_float4(x0*0.125f, x1*0.125f, x2*0.125f, x3*0.125f);
    } else if ((q >> 2) == c4) {
        ((float*)&v)[q & 3] = 1.f;
    }
    ((float4*)attns)[tid] = v;
}

// ---------------- fused relu-sum over sequence + decode + log_softmax ----------------
// grid BATCH, 512 threads: thread (e=t&255, half=t>>8) sums 256 rows.
__global__ __launch_bounds__(512)
void decode_fused(const __hip_bfloat16* __restrict__ xb, const float* __restrict__ dec_W,
                  float* __restrict__ out)
{
    int b = blockIdx.x, t = threadIdx.x;
    int e = t & 255, half = t >> 8;
    __shared__ float rs[2][256];
    {
        const __hip_bfloat16* xp = xb + ((size_t)b*SEQ + half*256)*EMB + e;
        float r = 0.f;
        for (int i = 0; i < 256; i++) r += fmaxf(__bfloat162float(xp[(size_t)i*EMB]), 0.f);
        rs[half][e] = r;
    }
    __syncthreads();
    float part[NCLS];
    if (t < 256) {
        float rr = rs[0][t] + rs[1][t];
        #pragma unroll
        for (int c = 0; c < NCLS; c++) part[c] = rr * dec_W[c*EMB + t];
    } else {
        #pragma unroll
        for (int c = 0; c < NCLS; c++) part[c] = 0.f;
    }
    #pragma unroll
    for (int o = 32; o; o >>= 1)
        #pragma unroll
        for (int c = 0; c < NCLS; c++) part[c] += __shfl_xor(part[c], o);
    __shared__ float red[8][NCLS];
    int wv = t >> 6, lane = t & 63;
    if (lane == 0)
        #pragma unroll
        for (int c = 0; c < NCLS; c++) red[wv][c] = part[c];
    __syncthreads();
    if (t == 0) {
        float lg[NCLS];
        float m = -1e30f;
        #pragma unroll
        for (int c = 0; c < NCLS; c++) {
            float s = 0.f;
            #pragma unroll
            for (int wvi = 0; wvi < 8; wvi++) s += red[wvi][c];
            lg[c] = s * (1.f/(float)SEQ);
            m = fmaxf(m, lg[c]);
        }
        float s = 0.f;
        #pragma unroll
        for (int c = 0; c < NCLS; c++) s += expf(lg[c] - m);
        float ls = logf(s);
        #pragma unroll
        for (int c = 0; c < NCLS; c++) out[b*NCLS + c] = lg[c] - m - ls;
    }
}

} // namespace

extern "C" void kernel_launch(void* const* d_in, const int* in_sizes, int n_in,
                              void* d_out, int out_size, void* d_ws, size_t ws_size,
                              hipStream_t stream)
{
    const float* src   = (const float*)d_in[0];
    const float* emb_W = (const float*)d_in[1];
    const float* emb_b = (const float*)d_in[2];
    const float* Wqkv  = (const float*)d_in[3];
    const float* bqkv  = (const float*)d_in[4];
    const float* Wo    = (const float*)d_in[5];
    const float* bo    = (const float*)d_in[6];
    const float* ln1_g = (const float*)d_in[7];
    const float* ln1_b = (const float*)d_in[8];
    const float* ln2_g = (const float*)d_in[9];
    const float* ln2_b = (const float*)d_in[10];
    const float* W1    = (const float*)d_in[11];
    const float* b1    = (const float*)d_in[12];
    const float* W2    = (const float*)d_in[13];
    const float* b2    = (const float*)d_in[14];
    const float* dec_W = (const float*)d_in[15];

    float* out   = (float*)d_out;               // [32,10]
    float* attns = out + BATCH*NCLS;            // [4,32,512,512]

    // workspace layout (~67 MB), no aliasing. x is bf16-only.
    char* ws = (char*)d_ws;
    __hip_bfloat16* xb16 = (__hip_bfloat16*)ws;     ws += (size_t)NTOK*EMB*2;     //  8.39 MB
    __hip_bfloat16* kbuf = (__hip_bfloat16*)ws;     ws += (size_t)NTOK*EMB*2;     //  8.39 MB
    __hip_bfloat16* vbuf = (__hip_bfloat16*)ws;     ws += (size_t)NTOK*EMB*2;     //  8.39 MB
    __hip_bfloat16* hbuf = (__hip_bfloat16*)ws;     ws += (size_t)NTOK*FF*2;      // 33.55 MB
    __hip_bfloat16* wq16 = (__hip_bfloat16*)ws;     ws += (size_t)NLAYER*3*EMB*EMB*2;
    __hip_bfloat16* wo16 = (__hip_bfloat16*)ws;     ws += (size_t)NLAYER*EMB*EMB*2;
    __hip_bfloat16* w116 = (__hip_bfloat16*)ws;     ws += (size_t)NLAYER*FF*EMB*2;
    __hip_bfloat16* w216 = (__hip_bfloat16*)ws;     ws += (size_t)NLAYER*EMB*FF*2;
    float*          amall= (float*)ws;              ws += (size_t)NLAYER*BATCH*NHEADS*SEQ*4; // 2.1 MB

    // weight conversion fp32 -> bf16 (single launch)
    f2b_all<<<3072, 256, 0, stream>>>(Wqkv, Wo, W1, W2, wq16, wo16, w116, w216);

    embed_kernel<<<NTOK, EMB, 0, stream>>>(src, emb_W, emb_b, xb16);

    for (int l = 0; l < NLAYER; l++) {
        const __hip_bfloat16* wql = wq16 + (size_t)l*3*EMB*EMB;
        const float* bql = bqkv + (size_t)l*3*EMB;

        // fused k|v projection: N=512 over W rows [E..3E)
        gemm_mfma<false, true><<<dim3(512/128, NTOK/128), 256, 0, stream>>>(
            xb16, EMB, wql + (size_t)EMB*EMB, bql + EMB, kbuf, vbuf, EMB, EMB);

        // fused per-(b,h): q GEMV + scores + softmax + per-head row + o_last
        attn_last_head<<<dim3(NHEADS, BATCH), 512, 0, stream>>>(
            xb16, wql, bql, kbuf, vbuf, amall + (size_t)l*BATCH*NHEADS*SEQ);

        // Wo GEMM + bias + residual + LN1 (in-place on xb16)
        gemm_ln<<<NTOK/32, 256, 0, stream>>>(
            vbuf, EMB, wo16 + (size_t)l*EMB*EMB, bo + (size_t)l*EMB,
            ln1_g + l*EMB, ln1_b + l*EMB, xb16, EMB);

        // FFN1 (relu, bf16 out)
        gemm_mfma<true, false><<<dim3(FF/128, NTOK/128), 256, 0, stream>>>(
            xb16, EMB, w116 + (size_t)l*FF*EMB, b1 + (size_t)l*FF, hbuf, nullptr, FF, EMB);

        // FFN2 GEMM + bias + residual + LN2 (in-place on xb16)
        gemm_ln<<<NTOK/32, 256, 0, stream>>>(
            hbuf, FF, w216 + (size_t)l*EMB*FF, b2 + (size_t)l*EMB,
            ln2_g + l*EMB, ln2_b + l*EMB, xb16, FF);
    }

    {
        size_t total_f4 = (size_t)NLAYER*BATCH*SEQ*(SEQ/4);
        int blocks = (int)((total_f4 + 255)/256);
        write_attns<<<blocks, 256, 0, stream>>>(attns, amall);
    }

    decode_fused<<<BATCH, 512, 0, stream>>>(xb16, dec_W, out);
}

// Round 12
// 486.223 us; speedup vs baseline: 1.1438x; 1.1243x over previous
//
#include <hip/hip_runtime.h>
#include <hip/hip_bf16.h>
#include <math.h>

namespace {

constexpr int BATCH = 32;
constexpr int SEQ   = 512;
constexpr int DIN   = 9;
constexpr int EMB   = 256;
constexpr int FF    = 1024;
constexpr int NLAYER= 4;
constexpr int NCLS  = 10;
constexpr int NHEADS= 8;
constexpr int HDIM  = 32;
constexpr int NTOK  = BATCH*SEQ;      // 16384

typedef __attribute__((ext_vector_type(8))) short short8;
typedef __attribute__((ext_vector_type(4))) float floatx4;

#define GLOAD_LDS16(g, l) __builtin_amdgcn_global_load_lds( \
    (const __attribute__((address_space(1))) unsigned*)(g), \
    (__attribute__((address_space(3))) unsigned*)(l), 16, 0, 0)

#define WAITCNT(N) asm volatile("s_waitcnt vmcnt(" #N ")" ::: "memory")

// ---------------- bf16 MFMA GEMM, 2-phase double-buffered (k|v projection) ----------------
template<bool RELU, bool KV>
__global__ __launch_bounds__(256)
void gemm_mfma(const __hip_bfloat16* __restrict__ A, int lda,
               const __hip_bfloat16* __restrict__ W,     // [N,K] row-major
               const float* __restrict__ bias,
               __hip_bfloat16* __restrict__ C0,
               __hip_bfloat16* __restrict__ C1,
               int ldc, int K)
{
    __shared__ __hip_bfloat16 As[2*128*32];
    __shared__ __hip_bfloat16 Bs[2*128*32];
    const int bm = blockIdx.y*128, bn = blockIdx.x*128;
    const int tid  = threadIdx.x;
    const int lane = tid & 63;
    const int w    = tid >> 6;
    const int wm   = (w >> 1)*64, wn = (w & 1)*64;

    floatx4 acc[4][4] = {};

    const int srow = w*32 + (lane >> 2);
    const int scol = (lane & 3)*8;
    const __hip_bfloat16* gA0 = A + (size_t)(bm + srow)*lda + scol;
    const __hip_bfloat16* gA1 = A + (size_t)(bm + srow + 16)*lda + scol;
    const __hip_bfloat16* gB0 = W + (size_t)(bn + srow)*K + scol;
    const __hip_bfloat16* gB1 = W + (size_t)(bn + srow + 16)*K + scol;
    const int l0 = (w*2)*512, l1 = (w*2 + 1)*512;

#define GM_STAGE(buf, k0) do { \
    GLOAD_LDS16(gA0 + (k0), As + (buf)*4096 + l0); \
    GLOAD_LDS16(gA1 + (k0), As + (buf)*4096 + l1); \
    GLOAD_LDS16(gB0 + (k0), Bs + (buf)*4096 + l0); \
    GLOAD_LDS16(gB1 + (k0), Bs + (buf)*4096 + l1); } while (0)

    const int arow = wm + (lane & 15);
    const int brow = wn + (lane & 15);
    const int kh   = lane >> 4;
    const int nt   = K >> 5;

    GM_STAGE(0, 0);
    for (int t = 0; t < nt; t++) {
        const int cur = t & 1;
        if (t + 1 < nt) {
            GM_STAGE(cur ^ 1, (t+1)*32);
            WAITCNT(4);
        } else {
            WAITCNT(0);
        }
        __builtin_amdgcn_s_barrier();
        const short8* Ab = (const short8*)(As + cur*4096);
        const short8* Bb = (const short8*)(Bs + cur*4096);
        short8 af[4], bf[4];
        #pragma unroll
        for (int m = 0; m < 4; m++) af[m] = Ab[(arow + m*16)*4 + kh];
        #pragma unroll
        for (int n = 0; n < 4; n++) bf[n] = Bb[(brow + n*16)*4 + kh];
        #pragma unroll
        for (int m = 0; m < 4; m++)
            #pragma unroll
            for (int n = 0; n < 4; n++)
                acc[m][n] = __builtin_amdgcn_mfma_f32_16x16x32_bf16(af[m], bf[n], acc[m][n], 0, 0, 0);
        __builtin_amdgcn_s_barrier();
    }
#undef GM_STAGE

    __hip_bfloat16* Cb;
    int cb;
    if (KV && bn >= 256) { Cb = C1; cb = bn - 256; }
    else                 { Cb = C0; cb = bn; }

    const int crow0 = bm + wm + (lane >> 4)*4;
    #pragma unroll
    for (int n = 0; n < 4; n++) {
        const int coln = wn + (lane & 15) + n*16;
        const float bv = bias[bn + coln];
        #pragma unroll
        for (int m = 0; m < 4; m++) {
            #pragma unroll
            for (int r = 0; r < 4; r++) {
                int row = crow0 + m*16 + r;
                float v = acc[m][n][r] + bv;
                if (RELU) v = fmaxf(v, 0.f);
                Cb[(size_t)row*ldc + cb + coln] = __float2bfloat16(v);
            }
        }
    }
}

// ---------------- helpers for the fused layer tail ----------------
__device__ __forceinline__ void stageB(const __hip_bfloat16* __restrict__ W, int ldw,
                                       int rowbase, int kbase,
                                       __hip_bfloat16* LB, int buf, int w, int lane)
{
    #pragma unroll
    for (int i = 0; i < 4; i++) {
        int rc = 4*w + i;
        const __hip_bfloat16* src = W + (size_t)(rowbase + rc*16 + (lane >> 2))*ldw
                                      + kbase + (lane & 3)*8;
        GLOAD_LDS16(src, LB + buf*8192 + rc*512);
    }
}

__device__ __forceinline__ void mfma8(const short8* Ab, const short8* Bb,
                                      floatx4* acc, int rgrp, int colhalf,
                                      int cl, int kh)
{
    short8 af = Ab[rgrp*64 + cl*4 + kh];
    #pragma unroll
    for (int n = 0; n < 8; n++) {
        short8 bf = Bb[(colhalf*8 + n)*64 + cl*4 + kh];
        acc[n] = __builtin_amdgcn_mfma_f32_16x16x32_bf16(af, bf, acc[n], 0, 0, 0);
    }
}

// ---------------- fused layer tail: Wo + res + LN1 + FFN1(relu) + FFN2 + res + LN2 ----------------
// 32-row blocks (512 blocks), 256 threads = 4 waves: rgrp = w&1 (16-row group),
// colhalf = w>>1 (128-col half). Row-local chain; x1 and FFN-hidden chunk in LDS
// (chunked [kwin][rowchunk][16r][32k] layout = MFMA staging layout).
__global__ __launch_bounds__(256, 2)
void layer_tail(const __hip_bfloat16* __restrict__ vbuf,  // [NTOK,256]
                const __hip_bfloat16* __restrict__ obuf,  // [BATCH,256] o_last rows
                const __hip_bfloat16* __restrict__ Wo,    // [256,256]
                const float* __restrict__ bo,
                const float* __restrict__ g1, const float* __restrict__ b1ln,
                const __hip_bfloat16* __restrict__ W1,    // [1024,256]
                const float* __restrict__ b1f,
                const __hip_bfloat16* __restrict__ W2,    // [256,1024]
                const float* __restrict__ b2f,
                const float* __restrict__ g2, const float* __restrict__ b2ln,
                __hip_bfloat16* __restrict__ xb16)        // in/out [NTOK,256]
{
    __shared__ __hip_bfloat16 SM[34816];                  // 68 KB
    __hip_bfloat16* LB = SM;                              // B staging, 2 x 8192
    __hip_bfloat16* LA = SM + 16384;                      // A staging, 2 x 1024 (+RED scratch)
    __hip_bfloat16* X1 = SM + 18432;                      // 8192 (32x256 chunked)
    __hip_bfloat16* HC = SM + 26624;                      // 8192 (32x256 chunked)
    float* RED = (float*)LA;                              // 128 floats, used post-K-loop

    const int bm   = blockIdx.x*32;
    const int tid  = threadIdx.x;
    const int lane = tid & 63;
    const int w    = tid >> 6;
    const int rgrp = w & 1;
    const int colhalf = w >> 1;
    const int cl   = lane & 15;
    const int rg   = lane >> 4;
    const int kh   = lane >> 4;                           // same as rg

    // ---- Phase 1: C1 = o @ Wo^T ;  x1 = LN1(x + C1 + bo) -> X1 (LDS) ----
    floatx4 acc[8] = {};
    const __hip_bfloat16* asrc = nullptr;
    if (w >= 2) {
        int a = w - 2;
        int grow = bm + a*16 + (lane >> 2);
        bool isl = (grow & (SEQ-1)) == (SEQ-1);
        asrc = (isl ? obuf + (size_t)(grow >> 9)*EMB
                    : vbuf + (size_t)grow*EMB) + (lane & 3)*8;
    }
    stageB(Wo, 256, 0, 0, LB, 0, w, lane);
    if (w >= 2) GLOAD_LDS16(asrc, LA + (w-2)*512);
    for (int t = 0; t < 8; t++) {
        const int cur = t & 1;
        if (t < 7) {
            stageB(Wo, 256, 0, (t+1)*32, LB, cur^1, w, lane);
            if (w >= 2) GLOAD_LDS16(asrc + (t+1)*32, LA + (cur^1)*1024 + (w-2)*512);
            WAITCNT(4);
        } else WAITCNT(0);
        __builtin_amdgcn_s_barrier();
        mfma8((const short8*)(LA + cur*1024), (const short8*)(LB + cur*8192),
              acc, rgrp, colhalf, cl, kh);
        __builtin_amdgcn_s_barrier();
    }
    // epilogue 1
    {
        float gv[8], bbv[8], bv[8];
        #pragma unroll
        for (int n = 0; n < 8; n++) {
            int col = colhalf*128 + n*16 + cl;
            bv[n] = bo[col]; gv[n] = g1[col]; bbv[n] = b1ln[col];
        }
        #pragma unroll
        for (int r = 0; r < 4; r++) {
            int row = bm + rgrp*16 + rg*4 + r;
            const __hip_bfloat16* xr = xb16 + (size_t)row*EMB + colhalf*128;
            float S = 0.f, Q = 0.f;
            #pragma unroll
            for (int n = 0; n < 8; n++) {
                float v = acc[n][r] + bv[n] + __bfloat162float(xr[n*16 + cl]);
                acc[n][r] = v; S += v; Q += v*v;
            }
            #pragma unroll
            for (int o = 1; o < 16; o <<= 1) { S += __shfl_xor(S, o); Q += __shfl_xor(Q, o); }
            if (cl == 0) {
                int idx = rgrp*16 + rg*4 + r;
                RED[colhalf*32 + idx] = S;
                RED[64 + colhalf*32 + idx] = Q;
            }
        }
        __syncthreads();
        #pragma unroll
        for (int r = 0; r < 4; r++) {
            int idx = rgrp*16 + rg*4 + r;
            float S = RED[idx] + RED[32 + idx];
            float Q = RED[64 + idx] + RED[96 + idx];
            float mean = S * (1.f/EMB);
            float var  = Q * (1.f/EMB) - mean*mean;
            float rstd = 1.f / sqrtf(var + 1e-5f);
            #pragma unroll
            for (int n = 0; n < 8; n++) {
                int col = colhalf*128 + n*16 + cl;
                float v = (acc[n][r] - mean)*rstd*gv[n] + bbv[n];
                X1[(col >> 5)*1024 + rgrp*512 + (rg*4 + r)*32 + (col & 31)] = __float2bfloat16(v);
            }
        }
        __syncthreads();
    }

    // ---- Phases 2+3 per 256-col chunk c: h_c = relu(x1 @ W1_c^T + b1) ; acc2 += h_c @ W2_c^T ----
    floatx4 acc2[8] = {};
    for (int c = 0; c < 4; c++) {
        // FFN1 chunk
        floatx4 fa[8] = {};
        stageB(W1, 256, c*256, 0, LB, 0, w, lane);
        for (int t = 0; t < 8; t++) {
            const int cur = t & 1;
            if (t < 7) { stageB(W1, 256, c*256, (t+1)*32, LB, cur^1, w, lane); WAITCNT(4); }
            else WAITCNT(0);
            __builtin_amdgcn_s_barrier();
            mfma8((const short8*)X1 + t*128, (const short8*)(LB + cur*8192),
                  fa, rgrp, colhalf, cl, kh);
            __builtin_amdgcn_s_barrier();
        }
        #pragma unroll
        for (int n = 0; n < 8; n++) {
            int colh = colhalf*128 + n*16 + cl;            // within chunk
            float bb = b1f[c*256 + colh];
            #pragma unroll
            for (int r = 0; r < 4; r++) {
                float v = fmaxf(fa[n][r] + bb, 0.f);
                HC[(colh >> 5)*1024 + rgrp*512 + (rg*4 + r)*32 + (colh & 31)] = __float2bfloat16(v);
            }
        }
        __syncthreads();
        // FFN2 partial (K = this chunk's 256 h-cols)
        stageB(W2, 1024, 0, c*256, LB, 0, w, lane);
        for (int t = 0; t < 8; t++) {
            const int cur = t & 1;
            if (t < 7) { stageB(W2, 1024, 0, c*256 + (t+1)*32, LB, cur^1, w, lane); WAITCNT(4); }
            else WAITCNT(0);
            __builtin_amdgcn_s_barrier();
            mfma8((const short8*)HC + t*128, (const short8*)(LB + cur*8192),
                  acc2, rgrp, colhalf, cl, kh);
            __builtin_amdgcn_s_barrier();
        }
    }

    // ---- epilogue 2: x = LN2(x1 + acc2 + b2) ----
    {
        float gv[8], bbv[8], bv[8];
        #pragma unroll
        for (int n = 0; n < 8; n++) {
            int col = colhalf*128 + n*16 + cl;
            bv[n] = b2f[col]; gv[n] = g2[col]; bbv[n] = b2ln[col];
        }
        #pragma unroll
        for (int r = 0; r < 4; r++) {
            float S = 0.f, Q = 0.f;
            #pragma unroll
            for (int n = 0; n < 8; n++) {
                int col = colhalf*128 + n*16 + cl;
                float x1v = __bfloat162float(X1[(col >> 5)*1024 + rgrp*512 + (rg*4 + r)*32 + (col & 31)]);
                float v = acc2[n][r] + bv[n] + x1v;
                acc2[n][r] = v; S += v; Q += v*v;
            }
            #pragma unroll
            for (int o = 1; o < 16; o <<= 1) { S += __shfl_xor(S, o); Q += __shfl_xor(Q, o); }
            if (cl == 0) {
                int idx = rgrp*16 + rg*4 + r;
                RED[colhalf*32 + idx] = S;
                RED[64 + colhalf*32 + idx] = Q;
            }
        }
        __syncthreads();
        #pragma unroll
        for (int r = 0; r < 4; r++) {
            int idx = rgrp*16 + rg*4 + r;
            int row = bm + idx;
            float S = RED[idx] + RED[32 + idx];
            float Q = RED[64 + idx] + RED[96 + idx];
            float mean = S * (1.f/EMB);
            float var  = Q * (1.f/EMB) - mean*mean;
            float rstd = 1.f / sqrtf(var + 1e-5f);
            __hip_bfloat16* xr = xb16 + (size_t)row*EMB + colhalf*128;
            #pragma unroll
            for (int n = 0; n < 8; n++) {
                float v = (acc2[n][r] - mean)*rstd*gv[n] + bbv[n];
                xr[n*16 + cl] = __float2bfloat16(v);
            }
        }
    }
}

// ---------------- fused fp32 -> bf16 weight conversion (all 4 arrays, 1 launch) ----------------
__global__ void f2b_all(const float* __restrict__ s0, const float* __restrict__ s1,
                        const float* __restrict__ s2, const float* __restrict__ s3,
                        __hip_bfloat16* __restrict__ d0, __hip_bfloat16* __restrict__ d1,
                        __hip_bfloat16* __restrict__ d2, __hip_bfloat16* __restrict__ d3)
{
    int blk = blockIdx.x;
    const float* s; __hip_bfloat16* d; int base;
    if      (blk <  768) { s = s0; d = d0; base = blk; }
    else if (blk < 1024) { s = s1; d = d1; base = blk - 768; }
    else if (blk < 2048) { s = s2; d = d2; base = blk - 1024; }
    else                 { s = s3; d = d3; base = blk - 2048; }
    int i = (base*256 + threadIdx.x)*4;
    float4 v = *(const float4*)(s + i);
    __hip_bfloat16 tmp[4];
    tmp[0] = __float2bfloat16(v.x); tmp[1] = __float2bfloat16(v.y);
    tmp[2] = __float2bfloat16(v.z); tmp[3] = __float2bfloat16(v.w);
    *(ushort4*)(d + i) = *(const ushort4*)tmp;
}

// ---------------- embed + scale + pos-enc; writes bf16 x ----------------
__global__ void embed_kernel(const float* __restrict__ src,
                             const float* __restrict__ emb_W,
                             const float* __restrict__ emb_b,
                             __hip_bfloat16* __restrict__ xb)
{
    int row = blockIdx.x;
    int e = threadIdx.x;
    int s = row % SEQ;
    const float* sr = src + (size_t)row*DIN;
    float acc = emb_b[e];
    #pragma unroll
    for (int d = 0; d < DIN; d++) acc += sr[d]*emb_W[e*DIN + d];
    acc *= 16.0f;                    // sqrt(EMB)
    int i2 = e & ~1;
    float div = expf(-(float)i2 * (9.210340371976184f / (float)EMB));
    float ang = (float)s * div;
    float pe = (e & 1) ? cosf(ang) : sinf(ang);
    xb[(size_t)row*EMB + e] = __float2bfloat16(acc + pe);
}

// ---------------- per-(b,h) last-row attention; o_last -> obuf ----------------
__global__ __launch_bounds__(512)
void attn_last_head(const __hip_bfloat16* __restrict__ xb,   // [NTOK, EMB] bf16
                    const __hip_bfloat16* __restrict__ Wq,   // [EMB, EMB] bf16 (q rows)
                    const float* __restrict__ bq,
                    const __hip_bfloat16* __restrict__ kbuf, // [B*S,256]
                    const __hip_bfloat16* __restrict__ vbuf, // [B*S,256]
                    __hip_bfloat16* __restrict__ obuf,       // [B,256]
                    float* __restrict__ amh)                 // [B*H, SEQ] for this layer
{
    const int h = blockIdx.x, b = blockIdx.y;
    const int t = threadIdx.x;                 // 0..511
    __shared__ float xlast[EMB];
    __shared__ float qpart[HDIM][17];
    __shared__ float qh[HDIM];
    __shared__ float sc[SEQ];
    __shared__ float red1[8], red2[8];
    __shared__ float opart[16][HDIM];

    if (t < EMB) xlast[t] = __bfloat162float(xb[((size_t)b*SEQ + SEQ-1)*EMB + t]);
    __syncthreads();

    {
        int d = t & 31, c = t >> 5;            // c in 0..15
        const __hip_bfloat16* wr = Wq + (size_t)(h*HDIM + d)*EMB + c*16;
        short8 w0 = *(const short8*)(wr);
        short8 w1 = *(const short8*)(wr + 8);
        float p = 0.f;
        #pragma unroll
        for (int j = 0; j < 8; j++)
            p += xlast[c*16 + j]*__bfloat162float(((const __hip_bfloat16*)&w0)[j]);
        #pragma unroll
        for (int j = 0; j < 8; j++)
            p += xlast[c*16 + 8 + j]*__bfloat162float(((const __hip_bfloat16*)&w1)[j]);
        qpart[d][c] = p;
    }
    __syncthreads();
    if (t < HDIM) {
        float qv = bq[h*HDIM + t];
        #pragma unroll
        for (int c = 0; c < 16; c++) qv += qpart[t][c];
        qh[t] = qv;
    }
    __syncthreads();

    {
        const __hip_bfloat16* krow = kbuf + ((size_t)b*SEQ + t)*EMB + h*HDIM;
        float s = 0.f;
        #pragma unroll
        for (int vv = 0; vv < 4; vv++) {
            short8 kk = *(const short8*)(krow + vv*8);
            #pragma unroll
            for (int j = 0; j < 8; j++)
                s += qh[vv*8 + j]*__bfloat162float(((const __hip_bfloat16*)&kk)[j]);
        }
        s *= 0.17677669529663687f;
        if (t == SEQ-1) s += -1e9f;
        sc[t] = s;
    }
    __syncthreads();

    {
        int wv = t >> 6, lane = t & 63;
        float m = sc[t];
        #pragma unroll
        for (int o = 32; o; o >>= 1) m = fmaxf(m, __shfl_xor(m, o));
        if (lane == 0) red1[wv] = m;
        __syncthreads();
        m = red1[0];
        #pragma unroll
        for (int i = 1; i < 8; i++) m = fmaxf(m, red1[i]);
        float e = expf(sc[t] - m);
        float s = e;
        #pragma unroll
        for (int o = 32; o; o >>= 1) s += __shfl_xor(s, o);
        if (lane == 0) red2[wv] = s;
        __syncthreads();
        float tot = red2[0]+red2[1]+red2[2]+red2[3]+red2[4]+red2[5]+red2[6]+red2[7];
        float a = e / tot;
        sc[t] = a;
        amh[((size_t)b*NHEADS + h)*SEQ + t] = a;
    }
    __syncthreads();

    {
        int e = t & 31, part = t >> 5;
        float o = 0.f;
        const __hip_bfloat16* vc = vbuf + (size_t)b*SEQ*EMB + h*HDIM + e;
        for (int k = part*32; k < part*32 + 32; k++)
            o += sc[k]*__bfloat162float(vc[(size_t)k*EMB]);
        opart[part][e] = o;
    }
    __syncthreads();
    if (t < HDIM) {
        float o = 0.f;
        #pragma unroll
        for (int p = 0; p < 16; p++) o += opart[p][t];
        obuf[b*EMB + h*HDIM + t] = __float2bfloat16(o);
    }
}

// ---------------- write full attns output [L,B,S,S]; head-avg fused for last rows ----------------
__global__ void write_attns(float* __restrict__ attns, const float* __restrict__ amh_all)
{
    constexpr int PER_ROW = SEQ/4;
    size_t tid = (size_t)blockIdx.x*blockDim.x + threadIdx.x;
    size_t row = tid / PER_ROW;
    int c4 = (int)(tid % PER_ROW);
    int q = (int)(row % SEQ);
    float4 v = make_float4(0.f,0.f,0.f,0.f);
    if (q == SEQ-1) {
        size_t lb = row / SEQ;
        const float* base = amh_all + lb*NHEADS*SEQ + c4*4;
        float x0=0.f, x1=0.f, x2=0.f, x3=0.f;
        #pragma unroll
        for (int h = 0; h < NHEADS; h++) {
            const float* r = base + (size_t)h*SEQ;
            x0 += r[0]; x1 += r[1]; x2 += r[2]; x3 += r[3];
        }
        v = make_float4(x0*0.125f, x1*0.125f, x2*0.125f, x3*0.125f);
    } else if ((q >> 2) == c4) {
        ((float*)&v)[q & 3] = 1.f;
    }
    ((float4*)attns)[tid] = v;
}

// ---------------- fused relu-sum over sequence + decode + log_softmax ----------------
__global__ __launch_bounds__(512)
void decode_fused(const __hip_bfloat16* __restrict__ xb, const float* __restrict__ dec_W,
                  float* __restrict__ out)
{
    int b = blockIdx.x, t = threadIdx.x;
    int e = t & 255, half = t >> 8;
    __shared__ float rs[2][256];
    {
        const __hip_bfloat16* xp = xb + ((size_t)b*SEQ + half*256)*EMB + e;
        float r = 0.f;
        for (int i = 0; i < 256; i++) r += fmaxf(__bfloat162float(xp[(size_t)i*EMB]), 0.f);
        rs[half][e] = r;
    }
    __syncthreads();
    float part[NCLS];
    if (t < 256) {
        float rr = rs[0][t] + rs[1][t];
        #pragma unroll
        for (int c = 0; c < NCLS; c++) part[c] = rr * dec_W[c*EMB + t];
    } else {
        #pragma unroll
        for (int c = 0; c < NCLS; c++) part[c] = 0.f;
    }
    #pragma unroll
    for (int o = 32; o; o >>= 1)
        #pragma unroll
        for (int c = 0; c < NCLS; c++) part[c] += __shfl_xor(part[c], o);
    __shared__ float red[8][NCLS];
    int wv = t >> 6, lane = t & 63;
    if (lane == 0)
        #pragma unroll
        for (int c = 0; c < NCLS; c++) red[wv][c] = part[c];
    __syncthreads();
    if (t == 0) {
        float lg[NCLS];
        float m = -1e30f;
        #pragma unroll
        for (int c = 0; c < NCLS; c++) {
            float s = 0.f;
            #pragma unroll
            for (int wvi = 0; wvi < 8; wvi++) s += red[wvi][c];
            lg[c] = s * (1.f/(float)SEQ);
            m = fmaxf(m, lg[c]);
        }
        float s = 0.f;
        #pragma unroll
        for (int c = 0; c < NCLS; c++) s += expf(lg[c] - m);
        float ls = logf(s);
        #pragma unroll
        for (int c = 0; c < NCLS; c++) out[b*NCLS + c] = lg[c] - m - ls;
    }
}

} // namespace

extern "C" void kernel_launch(void* const* d_in, const int* in_sizes, int n_in,
                              void* d_out, int out_size, void* d_ws, size_t ws_size,
                              hipStream_t stream)
{
    const float* src   = (const float*)d_in[0];
    const float* emb_W = (const float*)d_in[1];
    const float* emb_b = (const float*)d_in[2];
    const float* Wqkv  = (const float*)d_in[3];
    const float* bqkv  = (const float*)d_in[4];
    const float* Wo    = (const float*)d_in[5];
    const float* bo    = (const float*)d_in[6];
    const float* ln1_g = (const float*)d_in[7];
    const float* ln1_b = (const float*)d_in[8];
    const float* ln2_g = (const float*)d_in[9];
    const float* ln2_b = (const float*)d_in[10];
    const float* W1    = (const float*)d_in[11];
    const float* b1    = (const float*)d_in[12];
    const float* W2    = (const float*)d_in[13];
    const float* b2    = (const float*)d_in[14];
    const float* dec_W = (const float*)d_in[15];

    float* out   = (float*)d_out;               // [32,10]
    float* attns = out + BATCH*NCLS;            // [4,32,512,512]

    // workspace layout (~35 MB)
    char* ws = (char*)d_ws;
    __hip_bfloat16* xb16 = (__hip_bfloat16*)ws;     ws += (size_t)NTOK*EMB*2;     //  8.39 MB
    __hip_bfloat16* kbuf = (__hip_bfloat16*)ws;     ws += (size_t)NTOK*EMB*2;     //  8.39 MB
    __hip_bfloat16* vbuf = (__hip_bfloat16*)ws;     ws += (size_t)NTOK*EMB*2;     //  8.39 MB
    __hip_bfloat16* obuf = (__hip_bfloat16*)ws;     ws += (size_t)BATCH*EMB*2;
    __hip_bfloat16* wq16 = (__hip_bfloat16*)ws;     ws += (size_t)NLAYER*3*EMB*EMB*2;
    __hip_bfloat16* wo16 = (__hip_bfloat16*)ws;     ws += (size_t)NLAYER*EMB*EMB*2;
    __hip_bfloat16* w116 = (__hip_bfloat16*)ws;     ws += (size_t)NLAYER*FF*EMB*2;
    __hip_bfloat16* w216 = (__hip_bfloat16*)ws;     ws += (size_t)NLAYER*EMB*FF*2;
    float*          amall= (float*)ws;              ws += (size_t)NLAYER*BATCH*NHEADS*SEQ*4; // 2.1 MB

    // weight conversion fp32 -> bf16 (single launch)
    f2b_all<<<3072, 256, 0, stream>>>(Wqkv, Wo, W1, W2, wq16, wo16, w116, w216);

    embed_kernel<<<NTOK, EMB, 0, stream>>>(src, emb_W, emb_b, xb16);

    for (int l = 0; l < NLAYER; l++) {
        const __hip_bfloat16* wql = wq16 + (size_t)l*3*EMB*EMB;
        const float* bql = bqkv + (size_t)l*3*EMB;

        // fused k|v projection: N=512 over W rows [E..3E)
        gemm_mfma<false, true><<<dim3(512/128, NTOK/128), 256, 0, stream>>>(
            xb16, EMB, wql + (size_t)EMB*EMB, bql + EMB, kbuf, vbuf, EMB, EMB);

        // fused per-(b,h): q GEMV + scores + softmax + per-head row + o_last -> obuf
        attn_last_head<<<dim3(NHEADS, BATCH), 512, 0, stream>>>(
            xb16, wql, bql, kbuf, vbuf, obuf, amall + (size_t)l*BATCH*NHEADS*SEQ);

        // fused tail: Wo + res + LN1 + FFN1 + FFN2 + res + LN2 (in-place on xb16)
        layer_tail<<<NTOK/32, 256, 0, stream>>>(
            vbuf, obuf,
            wo16 + (size_t)l*EMB*EMB, bo + (size_t)l*EMB,
            ln1_g + l*EMB, ln1_b + l*EMB,
            w116 + (size_t)l*FF*EMB, b1 + (size_t)l*FF,
            w216 + (size_t)l*EMB*FF, b2 + (size_t)l*EMB,
            ln2_g + l*EMB, ln2_b + l*EMB,
            xb16);
    }

    {
        size_t total_f4 = (size_t)NLAYER*BATCH*SEQ*(SEQ/4);
        int blocks = (int)((total_f4 + 255)/256);
        write_attns<<<blocks, 256, 0, stream>>>(attns, amall);
    }

    decode_fused<<<BATCH, 512, 0, stream>>>(xb16, dec_W, out);
}

// Round 13
// 481.445 us; speedup vs baseline: 1.1551x; 1.0099x over previous
//
#include <hip/hip_runtime.h>
#include <hip/hip_bf16.h>
#include <math.h>

namespace {

constexpr int BATCH = 32;
constexpr int SEQ   = 512;
constexpr int DIN   = 9;
constexpr int EMB   = 256;
constexpr int FF    = 1024;
constexpr int NLAYER= 4;
constexpr int NCLS  = 10;
constexpr int NHEADS= 8;
constexpr int HDIM  = 32;
constexpr int NTOK  = BATCH*SEQ;      // 16384

typedef __attribute__((ext_vector_type(8))) short short8;
typedef __attribute__((ext_vector_type(4))) float floatx4;

#define GLOAD_LDS16(g, l) __builtin_amdgcn_global_load_lds( \
    (const __attribute__((address_space(1))) unsigned*)(g), \
    (__attribute__((address_space(3))) unsigned*)(l), 16, 0, 0)

#define WAITCNT(N) asm volatile("s_waitcnt vmcnt(" #N ")" ::: "memory")

// ---------------- bf16 MFMA GEMM, 2-phase double-buffered (layer-0 k|v projection) ----------------
template<bool RELU, bool KV>
__global__ __launch_bounds__(256)
void gemm_mfma(const __hip_bfloat16* __restrict__ A, int lda,
               const __hip_bfloat16* __restrict__ W,     // [N,K] row-major
               const float* __restrict__ bias,
               __hip_bfloat16* __restrict__ C0,
               __hip_bfloat16* __restrict__ C1,
               int ldc, int K)
{
    __shared__ __hip_bfloat16 As[2*128*32];
    __shared__ __hip_bfloat16 Bs[2*128*32];
    const int bm = blockIdx.y*128, bn = blockIdx.x*128;
    const int tid  = threadIdx.x;
    const int lane = tid & 63;
    const int w    = tid >> 6;
    const int wm   = (w >> 1)*64, wn = (w & 1)*64;

    floatx4 acc[4][4] = {};

    const int srow = w*32 + (lane >> 2);
    const int scol = (lane & 3)*8;
    const __hip_bfloat16* gA0 = A + (size_t)(bm + srow)*lda + scol;
    const __hip_bfloat16* gA1 = A + (size_t)(bm + srow + 16)*lda + scol;
    const __hip_bfloat16* gB0 = W + (size_t)(bn + srow)*K + scol;
    const __hip_bfloat16* gB1 = W + (size_t)(bn + srow + 16)*K + scol;
    const int l0 = (w*2)*512, l1 = (w*2 + 1)*512;

#define GM_STAGE(buf, k0) do { \
    GLOAD_LDS16(gA0 + (k0), As + (buf)*4096 + l0); \
    GLOAD_LDS16(gA1 + (k0), As + (buf)*4096 + l1); \
    GLOAD_LDS16(gB0 + (k0), Bs + (buf)*4096 + l0); \
    GLOAD_LDS16(gB1 + (k0), Bs + (buf)*4096 + l1); } while (0)

    const int arow = wm + (lane & 15);
    const int brow = wn + (lane & 15);
    const int kh   = lane >> 4;
    const int nt   = K >> 5;

    GM_STAGE(0, 0);
    for (int t = 0; t < nt; t++) {
        const int cur = t & 1;
        if (t + 1 < nt) {
            GM_STAGE(cur ^ 1, (t+1)*32);
            WAITCNT(4);
        } else {
            WAITCNT(0);
        }
        __builtin_amdgcn_s_barrier();
        const short8* Ab = (const short8*)(As + cur*4096);
        const short8* Bb = (const short8*)(Bs + cur*4096);
        short8 af[4], bf[4];
        #pragma unroll
        for (int m = 0; m < 4; m++) af[m] = Ab[(arow + m*16)*4 + kh];
        #pragma unroll
        for (int n = 0; n < 4; n++) bf[n] = Bb[(brow + n*16)*4 + kh];
        #pragma unroll
        for (int m = 0; m < 4; m++)
            #pragma unroll
            for (int n = 0; n < 4; n++)
                acc[m][n] = __builtin_amdgcn_mfma_f32_16x16x32_bf16(af[m], bf[n], acc[m][n], 0, 0, 0);
        __builtin_amdgcn_s_barrier();
    }
#undef GM_STAGE

    __hip_bfloat16* Cb;
    int cb;
    if (KV && bn >= 256) { Cb = C1; cb = bn - 256; }
    else                 { Cb = C0; cb = bn; }

    const int crow0 = bm + wm + (lane >> 4)*4;
    #pragma unroll
    for (int n = 0; n < 4; n++) {
        const int coln = wn + (lane & 15) + n*16;
        const float bv = bias[bn + coln];
        #pragma unroll
        for (int m = 0; m < 4; m++) {
            #pragma unroll
            for (int r = 0; r < 4; r++) {
                int row = crow0 + m*16 + r;
                float v = acc[m][n][r] + bv;
                if (RELU) v = fmaxf(v, 0.f);
                Cb[(size_t)row*ldc + cb + coln] = __float2bfloat16(v);
            }
        }
    }
}

// ---------------- helpers for the fused layer tail ----------------
__device__ __forceinline__ void stageB(const __hip_bfloat16* __restrict__ W, int ldw,
                                       int rowbase, int kbase,
                                       __hip_bfloat16* LB, int buf, int w, int lane)
{
    #pragma unroll
    for (int i = 0; i < 4; i++) {
        int rc = 4*w + i;
        const __hip_bfloat16* src = W + (size_t)(rowbase + rc*16 + (lane >> 2))*ldw
                                      + kbase + (lane & 3)*8;
        GLOAD_LDS16(src, LB + buf*8192 + rc*512);
    }
}

__device__ __forceinline__ void mfma8(const short8* Ab, const short8* Bb,
                                      floatx4* acc, int rgrp, int colhalf,
                                      int cl, int kh)
{
    short8 af = Ab[rgrp*64 + cl*4 + kh];
    #pragma unroll
    for (int n = 0; n < 8; n++) {
        short8 bf = Bb[(colhalf*8 + n)*64 + cl*4 + kh];
        acc[n] = __builtin_amdgcn_mfma_f32_16x16x32_bf16(af, bf, acc[n], 0, 0, 0);
    }
}

// ---------------- fused layer tail ----------------
// Wo + res + LN1 + FFN1(relu) + FFN2 + res + LN2 (+ optional next-layer k|v proj).
// 32-row blocks (512), 256 threads = 4 waves: rgrp = w&1 (16-row group),
// colhalf = w>>1 (128-col half).
__global__ __launch_bounds__(256, 2)
void layer_tail(const __hip_bfloat16* __restrict__ vbuf,  // [NTOK,256]
                const __hip_bfloat16* __restrict__ obuf,  // [BATCH,256] o_last rows
                const __hip_bfloat16* __restrict__ Wo,    // [256,256]
                const float* __restrict__ bo,
                const float* __restrict__ g1, const float* __restrict__ b1ln,
                const __hip_bfloat16* __restrict__ W1,    // [1024,256]
                const float* __restrict__ b1f,
                const __hip_bfloat16* __restrict__ W2,    // [256,1024]
                const float* __restrict__ b2f,
                const float* __restrict__ g2, const float* __restrict__ b2ln,
                __hip_bfloat16* __restrict__ xb16,        // in/out [NTOK,256]
                const __hip_bfloat16* __restrict__ Wkv,   // [512,256] next-layer k|v rows, or null
                const float* __restrict__ bk,
                const float* __restrict__ bv2,
                __hip_bfloat16* __restrict__ kout,
                __hip_bfloat16* __restrict__ vout)
{
    __shared__ __hip_bfloat16 SM[34816];                  // 68 KB
    __hip_bfloat16* LB = SM;                              // B staging, 2 x 8192
    __hip_bfloat16* LA = SM + 16384;                      // A staging, 2 x 1024 (+RED scratch)
    __hip_bfloat16* X1 = SM + 18432;                      // 8192 (32x256 chunked)
    __hip_bfloat16* HC = SM + 26624;                      // 8192 (32x256 chunked)
    float* RED = (float*)LA;                              // 128 floats, used post-K-loop

    const int bm   = blockIdx.x*32;
    const int tid  = threadIdx.x;
    const int lane = tid & 63;
    const int w    = tid >> 6;
    const int rgrp = w & 1;
    const int colhalf = w >> 1;
    const int cl   = lane & 15;
    const int rg   = lane >> 4;
    const int kh   = lane >> 4;

    // ---- Phase 1: C1 = o @ Wo^T ;  x1 = LN1(x + C1 + bo) -> X1 (LDS) ----
    floatx4 acc[8] = {};
    const __hip_bfloat16* asrc = nullptr;
    if (w >= 2) {
        int a = w - 2;
        int grow = bm + a*16 + (lane >> 2);
        bool isl = (grow & (SEQ-1)) == (SEQ-1);
        asrc = (isl ? obuf + (size_t)(grow >> 9)*EMB
                    : vbuf + (size_t)grow*EMB) + (lane & 3)*8;
    }
    stageB(Wo, 256, 0, 0, LB, 0, w, lane);
    if (w >= 2) GLOAD_LDS16(asrc, LA + (w-2)*512);
    for (int t = 0; t < 8; t++) {
        const int cur = t & 1;
        if (t < 7) {
            stageB(Wo, 256, 0, (t+1)*32, LB, cur^1, w, lane);
            if (w >= 2) GLOAD_LDS16(asrc + (t+1)*32, LA + (cur^1)*1024 + (w-2)*512);
            WAITCNT(4);
        } else WAITCNT(0);
        __builtin_amdgcn_s_barrier();
        mfma8((const short8*)(LA + cur*1024), (const short8*)(LB + cur*8192),
              acc, rgrp, colhalf, cl, kh);
        __builtin_amdgcn_s_barrier();
    }
    // epilogue 1
    {
        float gv[8], bbv[8], bv[8];
        #pragma unroll
        for (int n = 0; n < 8; n++) {
            int col = colhalf*128 + n*16 + cl;
            bv[n] = bo[col]; gv[n] = g1[col]; bbv[n] = b1ln[col];
        }
        #pragma unroll
        for (int r = 0; r < 4; r++) {
            int row = bm + rgrp*16 + rg*4 + r;
            const __hip_bfloat16* xr = xb16 + (size_t)row*EMB + colhalf*128;
            float S = 0.f, Q = 0.f;
            #pragma unroll
            for (int n = 0; n < 8; n++) {
                float v = acc[n][r] + bv[n] + __bfloat162float(xr[n*16 + cl]);
                acc[n][r] = v; S += v; Q += v*v;
            }
            #pragma unroll
            for (int o = 1; o < 16; o <<= 1) { S += __shfl_xor(S, o); Q += __shfl_xor(Q, o); }
            if (cl == 0) {
                int idx = rgrp*16 + rg*4 + r;
                RED[colhalf*32 + idx] = S;
                RED[64 + colhalf*32 + idx] = Q;
            }
        }
        __syncthreads();
        #pragma unroll
        for (int r = 0; r < 4; r++) {
            int idx = rgrp*16 + rg*4 + r;
            float S = RED[idx] + RED[32 + idx];
            float Q = RED[64 + idx] + RED[96 + idx];
            float mean = S * (1.f/EMB);
            float var  = Q * (1.f/EMB) - mean*mean;
            float rstd = 1.f / sqrtf(var + 1e-5f);
            #pragma unroll
            for (int n = 0; n < 8; n++) {
                int col = colhalf*128 + n*16 + cl;
                float v = (acc[n][r] - mean)*rstd*gv[n] + bbv[n];
                X1[(col >> 5)*1024 + rgrp*512 + (rg*4 + r)*32 + (col & 31)] = __float2bfloat16(v);
            }
        }
        __syncthreads();
    }

    // ---- Phases 2+3 per 256-col chunk c: h_c = relu(x1 @ W1_c^T + b1) ; acc2 += h_c @ W2_c^T ----
    floatx4 acc2[8] = {};
    for (int c = 0; c < 4; c++) {
        floatx4 fa[8] = {};
        stageB(W1, 256, c*256, 0, LB, 0, w, lane);
        for (int t = 0; t < 8; t++) {
            const int cur = t & 1;
            if (t < 7) { stageB(W1, 256, c*256, (t+1)*32, LB, cur^1, w, lane); WAITCNT(4); }
            else WAITCNT(0);
            __builtin_amdgcn_s_barrier();
            mfma8((const short8*)X1 + t*128, (const short8*)(LB + cur*8192),
                  fa, rgrp, colhalf, cl, kh);
            __builtin_amdgcn_s_barrier();
        }
        #pragma unroll
        for (int n = 0; n < 8; n++) {
            int colh = colhalf*128 + n*16 + cl;
            float bb = b1f[c*256 + colh];
            #pragma unroll
            for (int r = 0; r < 4; r++) {
                float v = fmaxf(fa[n][r] + bb, 0.f);
                HC[(colh >> 5)*1024 + rgrp*512 + (rg*4 + r)*32 + (colh & 31)] = __float2bfloat16(v);
            }
        }
        __syncthreads();
        stageB(W2, 1024, 0, c*256, LB, 0, w, lane);
        for (int t = 0; t < 8; t++) {
            const int cur = t & 1;
            if (t < 7) { stageB(W2, 1024, 0, c*256 + (t+1)*32, LB, cur^1, w, lane); WAITCNT(4); }
            else WAITCNT(0);
            __builtin_amdgcn_s_barrier();
            mfma8((const short8*)HC + t*128, (const short8*)(LB + cur*8192),
                  acc2, rgrp, colhalf, cl, kh);
            __builtin_amdgcn_s_barrier();
        }
    }

    // ---- epilogue 2: x = LN2(x1 + acc2 + b2); also chunk new x into HC for phase 4 ----
    {
        float gv[8], bbv[8], bv[8];
        #pragma unroll
        for (int n = 0; n < 8; n++) {
            int col = colhalf*128 + n*16 + cl;
            bv[n] = b2f[col]; gv[n] = g2[col]; bbv[n] = b2ln[col];
        }
        #pragma unroll
        for (int r = 0; r < 4; r++) {
            float S = 0.f, Q = 0.f;
            #pragma unroll
            for (int n = 0; n < 8; n++) {
                int col = colhalf*128 + n*16 + cl;
                float x1v = __bfloat162float(X1[(col >> 5)*1024 + rgrp*512 + (rg*4 + r)*32 + (col & 31)]);
                float v = acc2[n][r] + bv[n] + x1v;
                acc2[n][r] = v; S += v; Q += v*v;
            }
            #pragma unroll
            for (int o = 1; o < 16; o <<= 1) { S += __shfl_xor(S, o); Q += __shfl_xor(Q, o); }
            if (cl == 0) {
                int idx = rgrp*16 + rg*4 + r;
                RED[colhalf*32 + idx] = S;
                RED[64 + colhalf*32 + idx] = Q;
            }
        }
        __syncthreads();
        #pragma unroll
        for (int r = 0; r < 4; r++) {
            int idx = rgrp*16 + rg*4 + r;
            int row = bm + idx;
            float S = RED[idx] + RED[32 + idx];
            float Q = RED[64 + idx] + RED[96 + idx];
            float mean = S * (1.f/EMB);
            float var  = Q * (1.f/EMB) - mean*mean;
            float rstd = 1.f / sqrtf(var + 1e-5f);
            __hip_bfloat16* xr = xb16 + (size_t)row*EMB + colhalf*128;
            #pragma unroll
            for (int n = 0; n < 8; n++) {
                int col = colhalf*128 + n*16 + cl;
                float v = (acc2[n][r] - mean)*rstd*gv[n] + bbv[n];
                __hip_bfloat16 hv = __float2bfloat16(v);
                xr[n*16 + cl] = hv;
                HC[(col >> 5)*1024 + rgrp*512 + (rg*4 + r)*32 + (col & 31)] = hv;
            }
        }
    }

    // ---- Phase 4 (optional): next-layer k|v = x @ Wkv^T + b ----
    if (Wkv != nullptr) {
        __syncthreads();                       // HC (new x) visible to all waves
        #pragma unroll
        for (int nh = 0; nh < 2; nh++) {
            floatx4 a3[8] = {};
            const float* bkv = (nh == 0) ? bk : bv2;
            __hip_bfloat16* dst = (nh == 0) ? kout : vout;
            stageB(Wkv, 256, nh*256, 0, LB, 0, w, lane);
            for (int t = 0; t < 8; t++) {
                const int cur = t & 1;
                if (t < 7) { stageB(Wkv, 256, nh*256, (t+1)*32, LB, cur^1, w, lane); WAITCNT(4); }
                else WAITCNT(0);
                __builtin_amdgcn_s_barrier();
                mfma8((const short8*)HC + t*128, (const short8*)(LB + cur*8192),
                      a3, rgrp, colhalf, cl, kh);
                __builtin_amdgcn_s_barrier();
            }
            #pragma unroll
            for (int n = 0; n < 8; n++) {
                int col = colhalf*128 + n*16 + cl;
                float bb = bkv[col];
                #pragma unroll
                for (int r = 0; r < 4; r++) {
                    int row = bm + rgrp*16 + rg*4 + r;
                    dst[(size_t)row*EMB + col] = __float2bfloat16(a3[n][r] + bb);
                }
            }
        }
    }
}

// ---------------- fused fp32 -> bf16 weight conversion (all 4 arrays, 1 launch) ----------------
__global__ void f2b_all(const float* __restrict__ s0, const float* __restrict__ s1,
                        const float* __restrict__ s2, const float* __restrict__ s3,
                        __hip_bfloat16* __restrict__ d0, __hip_bfloat16* __restrict__ d1,
                        __hip_bfloat16* __restrict__ d2, __hip_bfloat16* __restrict__ d3)
{
    int blk = blockIdx.x;
    const float* s; __hip_bfloat16* d; int base;
    if      (blk <  768) { s = s0; d = d0; base = blk; }
    else if (blk < 1024) { s = s1; d = d1; base = blk - 768; }
    else if (blk < 2048) { s = s2; d = d2; base = blk - 1024; }
    else                 { s = s3; d = d3; base = blk - 2048; }
    int i = (base*256 + threadIdx.x)*4;
    float4 v = *(const float4*)(s + i);
    __hip_bfloat16 tmp[4];
    tmp[0] = __float2bfloat16(v.x); tmp[1] = __float2bfloat16(v.y);
    tmp[2] = __float2bfloat16(v.z); tmp[3] = __float2bfloat16(v.w);
    *(ushort4*)(d + i) = *(const ushort4*)tmp;
}

// ---------------- embed + scale + pos-enc; writes bf16 x ----------------
__global__ void embed_kernel(const float* __restrict__ src,
                             const float* __restrict__ emb_W,
                             const float* __restrict__ emb_b,
                             __hip_bfloat16* __restrict__ xb)
{
    int row = blockIdx.x;
    int e = threadIdx.x;
    int s = row % SEQ;
    const float* sr = src + (size_t)row*DIN;
    float acc = emb_b[e];
    #pragma unroll
    for (int d = 0; d < DIN; d++) acc += sr[d]*emb_W[e*DIN + d];
    acc *= 16.0f;                    // sqrt(EMB)
    int i2 = e & ~1;
    float div = expf(-(float)i2 * (9.210340371976184f / (float)EMB));
    float ang = (float)s * div;
    float pe = (e & 1) ? cosf(ang) : sinf(ang);
    xb[(size_t)row*EMB + e] = __float2bfloat16(acc + pe);
}

// ---------------- per-(b,h) last-row attention; o_last -> obuf ----------------
__global__ __launch_bounds__(512)
void attn_last_head(const __hip_bfloat16* __restrict__ xb,   // [NTOK, EMB] bf16
                    const __hip_bfloat16* __restrict__ Wq,   // [EMB, EMB] bf16 (q rows)
                    const float* __restrict__ bq,
                    const __hip_bfloat16* __restrict__ kbuf, // [B*S,256]
                    const __hip_bfloat16* __restrict__ vbuf, // [B*S,256]
                    __hip_bfloat16* __restrict__ obuf,       // [B,256]
                    float* __restrict__ amh)                 // [B*H, SEQ] for this layer
{
    const int h = blockIdx.x, b = blockIdx.y;
    const int t = threadIdx.x;                 // 0..511
    __shared__ float xlast[EMB];
    __shared__ float qpart[HDIM][17];
    __shared__ float qh[HDIM];
    __shared__ float sc[SEQ];
    __shared__ float red1[8], red2[8];
    __shared__ float opart[16][HDIM];

    if (t < EMB) xlast[t] = __bfloat162float(xb[((size_t)b*SEQ + SEQ-1)*EMB + t]);
    __syncthreads();

    {
        int d = t & 31, c = t >> 5;            // c in 0..15
        const __hip_bfloat16* wr = Wq + (size_t)(h*HDIM + d)*EMB + c*16;
        short8 w0 = *(const short8*)(wr);
        short8 w1 = *(const short8*)(wr + 8);
        float p = 0.f;
        #pragma unroll
        for (int j = 0; j < 8; j++)
            p += xlast[c*16 + j]*__bfloat162float(((const __hip_bfloat16*)&w0)[j]);
        #pragma unroll
        for (int j = 0; j < 8; j++)
            p += xlast[c*16 + 8 + j]*__bfloat162float(((const __hip_bfloat16*)&w1)[j]);
        qpart[d][c] = p;
    }
    __syncthreads();
    if (t < HDIM) {
        float qv = bq[h*HDIM + t];
        #pragma unroll
        for (int c = 0; c < 16; c++) qv += qpart[t][c];
        qh[t] = qv;
    }
    __syncthreads();

    {
        const __hip_bfloat16* krow = kbuf + ((size_t)b*SEQ + t)*EMB + h*HDIM;
        float s = 0.f;
        #pragma unroll
        for (int vv = 0; vv < 4; vv++) {
            short8 kk = *(const short8*)(krow + vv*8);
            #pragma unroll
            for (int j = 0; j < 8; j++)
                s += qh[vv*8 + j]*__bfloat162float(((const __hip_bfloat16*)&kk)[j]);
        }
        s *= 0.17677669529663687f;
        if (t == SEQ-1) s += -1e9f;
        sc[t] = s;
    }
    __syncthreads();

    {
        int wv = t >> 6, lane = t & 63;
        float m = sc[t];
        #pragma unroll
        for (int o = 32; o; o >>= 1) m = fmaxf(m, __shfl_xor(m, o));
        if (lane == 0) red1[wv] = m;
        __syncthreads();
        m = red1[0];
        #pragma unroll
        for (int i = 1; i < 8; i++) m = fmaxf(m, red1[i]);
        float e = expf(sc[t] - m);
        float s = e;
        #pragma unroll
        for (int o = 32; o; o >>= 1) s += __shfl_xor(s, o);
        if (lane == 0) red2[wv] = s;
        __syncthreads();
        float tot = red2[0]+red2[1]+red2[2]+red2[3]+red2[4]+red2[5]+red2[6]+red2[7];
        float a = e / tot;
        sc[t] = a;
        amh[((size_t)b*NHEADS + h)*SEQ + t] = a;
    }
    __syncthreads();

    {
        int e = t & 31, part = t >> 5;
        float o = 0.f;
        const __hip_bfloat16* vc = vbuf + (size_t)b*SEQ*EMB + h*HDIM + e;
        for (int k = part*32; k < part*32 + 32; k++)
            o += sc[k]*__bfloat162float(vc[(size_t)k*EMB]);
        opart[part][e] = o;
    }
    __syncthreads();
    if (t < HDIM) {
        float o = 0.f;
        #pragma unroll
        for (int p = 0; p < 16; p++) o += opart[p][t];
        obuf[b*EMB + h*HDIM + t] = __float2bfloat16(o);
    }
}

// ---------------- write full attns output [L,B,S,S]; head-avg fused for last rows ----------------
__global__ void write_attns(float* __restrict__ attns, const float* __restrict__ amh_all)
{
    constexpr int PER_ROW = SEQ/4;
    size_t tid = (size_t)blockIdx.x*blockDim.x + threadIdx.x;
    size_t row = tid / PER_ROW;
    int c4 = (int)(tid % PER_ROW);
    int q = (int)(row % SEQ);
    float4 v = make_float4(0.f,0.f,0.f,0.f);
    if (q == SEQ-1) {
        size_t lb = row / SEQ;
        const float* base = amh_all + lb*NHEADS*SEQ + c4*4;
        float x0=0.f, x1=0.f, x2=0.f, x3=0.f;
        #pragma unroll
        for (int h = 0; h < NHEADS; h++) {
            const float* r = base + (size_t)h*SEQ;
            x0 += r[0]; x1 += r[1]; x2 += r[2]; x3 += r[3];
        }
        v = make_float4(x0*0.125f, x1*0.125f, x2*0.125f, x3*0.125f);
    } else if ((q >> 2) == c4) {
        ((float*)&v)[q & 3] = 1.f;
    }
    ((float4*)attns)[tid] = v;
}

// ---------------- fused relu-sum over sequence + decode + log_softmax ----------------
__global__ __launch_bounds__(512)
void decode_fused(const __hip_bfloat16* __restrict__ xb, const float* __restrict__ dec_W,
                  float* __restrict__ out)
{
    int b = blockIdx.x, t = threadIdx.x;
    int e = t & 255, half = t >> 8;
    __shared__ float rs[2][256];
    {
        const __hip_bfloat16* xp = xb + ((size_t)b*SEQ + half*256)*EMB + e;
        float r = 0.f;
        for (int i = 0; i < 256; i++) r += fmaxf(__bfloat162float(xp[(size_t)i*EMB]), 0.f);
        rs[half][e] = r;
    }
    __syncthreads();
    float part[NCLS];
    if (t < 256) {
        float rr = rs[0][t] + rs[1][t];
        #pragma unroll
        for (int c = 0; c < NCLS; c++) part[c] = rr * dec_W[c*EMB + t];
    } else {
        #pragma unroll
        for (int c = 0; c < NCLS; c++) part[c] = 0.f;
    }
    #pragma unroll
    for (int o = 32; o; o >>= 1)
        #pragma unroll
        for (int c = 0; c < NCLS; c++) part[c] += __shfl_xor(part[c], o);
    __shared__ float red[8][NCLS];
    int wv = t >> 6, lane = t & 63;
    if (lane == 0)
        #pragma unroll
        for (int c = 0; c < NCLS; c++) red[wv][c] = part[c];
    __syncthreads();
    if (t == 0) {
        float lg[NCLS];
        float m = -1e30f;
        #pragma unroll
        for (int c = 0; c < NCLS; c++) {
            float s = 0.f;
            #pragma unroll
            for (int wvi = 0; wvi < 8; wvi++) s += red[wvi][c];
            lg[c] = s * (1.f/(float)SEQ);
            m = fmaxf(m, lg[c]);
        }
        float s = 0.f;
        #pragma unroll
        for (int c = 0; c < NCLS; c++) s += expf(lg[c] - m);
        float ls = logf(s);
        #pragma unroll
        for (int c = 0; c < NCLS; c++) out[b*NCLS + c] = lg[c] - m - ls;
    }
}

} // namespace

extern "C" void kernel_launch(void* const* d_in, const int* in_sizes, int n_in,
                              void* d_out, int out_size, void* d_ws, size_t ws_size,
                              hipStream_t stream)
{
    const float* src   = (const float*)d_in[0];
    const float* emb_W = (const float*)d_in[1];
    const float* emb_b = (const float*)d_in[2];
    const float* Wqkv  = (const float*)d_in[3];
    const float* bqkv  = (const float*)d_in[4];
    const float* Wo    = (const float*)d_in[5];
    const float* bo    = (const float*)d_in[6];
    const float* ln1_g = (const float*)d_in[7];
    const float* ln1_b = (const float*)d_in[8];
    const float* ln2_g = (const float*)d_in[9];
    const float* ln2_b = (const float*)d_in[10];
    const float* W1    = (const float*)d_in[11];
    const float* b1    = (const float*)d_in[12];
    const float* W2    = (const float*)d_in[13];
    const float* b2    = (const float*)d_in[14];
    const float* dec_W = (const float*)d_in[15];

    float* out   = (float*)d_out;               // [32,10]
    float* attns = out + BATCH*NCLS;            // [4,32,512,512]

    // workspace layout (~35 MB)
    char* ws = (char*)d_ws;
    __hip_bfloat16* xb16 = (__hip_bfloat16*)ws;     ws += (size_t)NTOK*EMB*2;     //  8.39 MB
    __hip_bfloat16* kbuf = (__hip_bfloat16*)ws;     ws += (size_t)NTOK*EMB*2;     //  8.39 MB
    __hip_bfloat16* vbuf = (__hip_bfloat16*)ws;     ws += (size_t)NTOK*EMB*2;     //  8.39 MB
    __hip_bfloat16* obuf = (__hip_bfloat16*)ws;     ws += (size_t)BATCH*EMB*2;
    __hip_bfloat16* wq16 = (__hip_bfloat16*)ws;     ws += (size_t)NLAYER*3*EMB*EMB*2;
    __hip_bfloat16* wo16 = (__hip_bfloat16*)ws;     ws += (size_t)NLAYER*EMB*EMB*2;
    __hip_bfloat16* w116 = (__hip_bfloat16*)ws;     ws += (size_t)NLAYER*FF*EMB*2;
    __hip_bfloat16* w216 = (__hip_bfloat16*)ws;     ws += (size_t)NLAYER*EMB*FF*2;
    float*          amall= (float*)ws;              ws += (size_t)NLAYER*BATCH*NHEADS*SEQ*4; // 2.1 MB

    // weight conversion fp32 -> bf16 (single launch)
    f2b_all<<<3072, 256, 0, stream>>>(Wqkv, Wo, W1, W2, wq16, wo16, w116, w216);

    embed_kernel<<<NTOK, EMB, 0, stream>>>(src, emb_W, emb_b, xb16);

    // layer-0 k|v projection (subsequent layers' kv fused into layer_tail)
    gemm_mfma<false, true><<<dim3(512/128, NTOK/128), 256, 0, stream>>>(
        xb16, EMB, wq16 + (size_t)EMB*EMB, bqkv + EMB, kbuf, vbuf, EMB, EMB);

    for (int l = 0; l < NLAYER; l++) {
        const __hip_bfloat16* wql = wq16 + (size_t)l*3*EMB*EMB;
        const float* bql = bqkv + (size_t)l*3*EMB;

        // fused per-(b,h): q GEMV + scores + softmax + per-head row + o_last -> obuf
        attn_last_head<<<dim3(NHEADS, BATCH), 512, 0, stream>>>(
            xb16, wql, bql, kbuf, vbuf, obuf, amall + (size_t)l*BATCH*NHEADS*SEQ);

        // fused tail: Wo + res + LN1 + FFN1 + FFN2 + res + LN2 (+ next-layer kv)
        const bool last = (l == NLAYER-1);
        const __hip_bfloat16* wkv_next = last ? nullptr
            : wq16 + (size_t)(l+1)*3*EMB*EMB + (size_t)EMB*EMB;
        const float* bk_next = last ? nullptr : bqkv + (size_t)(l+1)*3*EMB + EMB;
        const float* bv_next = last ? nullptr : bqkv + (size_t)(l+1)*3*EMB + 2*EMB;
        layer_tail<<<NTOK/32, 256, 0, stream>>>(
            vbuf, obuf,
            wo16 + (size_t)l*EMB*EMB, bo + (size_t)l*EMB,
            ln1_g + l*EMB, ln1_b + l*EMB,
            w116 + (size_t)l*FF*EMB, b1 + (size_t)l*FF,
            w216 + (size_t)l*EMB*FF, b2 + (size_t)l*EMB,
            ln2_g + l*EMB, ln2_b + l*EMB,
            xb16,
            wkv_next, bk_next, bv_next,
            last ? nullptr : kbuf, last ? nullptr : vbuf);
    }

    {
        size_t total_f4 = (size_t)NLAYER*BATCH*SEQ*(SEQ/4);
        int blocks = (int)((total_f4 + 255)/256);
        write_attns<<<blocks, 256, 0, stream>>>(attns, amall);
    }

    decode_fused<<<BATCH, 512, 0, stream>>>(xb16, dec_W, out);
}

// Round 14
// 444.469 us; speedup vs baseline: 1.2512x; 1.0832x over previous
//
#include <hip/hip_runtime.h>
#include <hip/hip_bf16.h>
#include <math.h>

namespace {

constexpr int BATCH = 32;
constexpr int SEQ   = 512;
constexpr int DIN   = 9;
constexpr int EMB   = 256;
constexpr int FF    = 1024;
constexpr int NLAYER= 4;
constexpr int NCLS  = 10;
constexpr int NHEADS= 8;
constexpr int HDIM  = 32;
constexpr int NTOK  = BATCH*SEQ;      // 16384

typedef __attribute__((ext_vector_type(8))) short short8;
typedef __attribute__((ext_vector_type(4))) float floatx4;

#define GLOAD_LDS16(g, l) __builtin_amdgcn_global_load_lds( \
    (const __attribute__((address_space(1))) unsigned*)(g), \
    (__attribute__((address_space(3))) unsigned*)(l), 16, 0, 0)

#define WAITCNT(N) asm volatile("s_waitcnt vmcnt(" #N ")" ::: "memory")

// ---------------- bf16 MFMA GEMM, 2-phase double-buffered (layer-0 k|v projection) ----------------
template<bool RELU, bool KV>
__global__ __launch_bounds__(256)
void gemm_mfma(const __hip_bfloat16* __restrict__ A, int lda,
               const __hip_bfloat16* __restrict__ W,     // [N,K] row-major
               const float* __restrict__ bias,
               __hip_bfloat16* __restrict__ C0,
               __hip_bfloat16* __restrict__ C1,
               int ldc, int K)
{
    __shared__ __hip_bfloat16 As[2*128*32];
    __shared__ __hip_bfloat16 Bs[2*128*32];
    const int bm = blockIdx.y*128, bn = blockIdx.x*128;
    const int tid  = threadIdx.x;
    const int lane = tid & 63;
    const int w    = tid >> 6;
    const int wm   = (w >> 1)*64, wn = (w & 1)*64;

    floatx4 acc[4][4] = {};

    const int srow = w*32 + (lane >> 2);
    const int scol = (lane & 3)*8;
    const __hip_bfloat16* gA0 = A + (size_t)(bm + srow)*lda + scol;
    const __hip_bfloat16* gA1 = A + (size_t)(bm + srow + 16)*lda + scol;
    const __hip_bfloat16* gB0 = W + (size_t)(bn + srow)*K + scol;
    const __hip_bfloat16* gB1 = W + (size_t)(bn + srow + 16)*K + scol;
    const int l0 = (w*2)*512, l1 = (w*2 + 1)*512;

#define GM_STAGE(buf, k0) do { \
    GLOAD_LDS16(gA0 + (k0), As + (buf)*4096 + l0); \
    GLOAD_LDS16(gA1 + (k0), As + (buf)*4096 + l1); \
    GLOAD_LDS16(gB0 + (k0), Bs + (buf)*4096 + l0); \
    GLOAD_LDS16(gB1 + (k0), Bs + (buf)*4096 + l1); } while (0)

    const int arow = wm + (lane & 15);
    const int brow = wn + (lane & 15);
    const int kh   = lane >> 4;
    const int nt   = K >> 5;

    GM_STAGE(0, 0);
    for (int t = 0; t < nt; t++) {
        const int cur = t & 1;
        if (t + 1 < nt) {
            GM_STAGE(cur ^ 1, (t+1)*32);
            WAITCNT(4);
        } else {
            WAITCNT(0);
        }
        __builtin_amdgcn_s_barrier();
        const short8* Ab = (const short8*)(As + cur*4096);
        const short8* Bb = (const short8*)(Bs + cur*4096);
        short8 af[4], bf[4];
        #pragma unroll
        for (int m = 0; m < 4; m++) af[m] = Ab[(arow + m*16)*4 + kh];
        #pragma unroll
        for (int n = 0; n < 4; n++) bf[n] = Bb[(brow + n*16)*4 + kh];
        #pragma unroll
        for (int m = 0; m < 4; m++)
            #pragma unroll
            for (int n = 0; n < 4; n++)
                acc[m][n] = __builtin_amdgcn_mfma_f32_16x16x32_bf16(af[m], bf[n], acc[m][n], 0, 0, 0);
        __builtin_amdgcn_s_barrier();
    }
#undef GM_STAGE

    __hip_bfloat16* Cb;
    int cb;
    if (KV && bn >= 256) { Cb = C1; cb = bn - 256; }
    else                 { Cb = C0; cb = bn; }

    const int crow0 = bm + wm + (lane >> 4)*4;
    #pragma unroll
    for (int n = 0; n < 4; n++) {
        const int coln = wn + (lane & 15) + n*16;
        const float bv = bias[bn + coln];
        #pragma unroll
        for (int m = 0; m < 4; m++) {
            #pragma unroll
            for (int r = 0; r < 4; r++) {
                int row = crow0 + m*16 + r;
                float v = acc[m][n][r] + bv;
                if (RELU) v = fmaxf(v, 0.f);
                Cb[(size_t)row*ldc + cb + coln] = __float2bfloat16(v);
            }
        }
    }
}

// ---------------- helpers for the fused layer tail (BM=64, 8 waves) ----------------
// stage the full 256-row x 32-k B slab: 16 chunks, 2 per wave
__device__ __forceinline__ void stageB64(const __hip_bfloat16* __restrict__ W, int ldw,
                                         int rowbase, int kbase,
                                         __hip_bfloat16* LB, int buf, int w, int lane)
{
    #pragma unroll
    for (int i = 0; i < 2; i++) {
        int rc = 2*w + i;
        const __hip_bfloat16* src = W + (size_t)(rowbase + rc*16 + (lane >> 2))*ldw
                                      + kbase + (lane & 3)*8;
        GLOAD_LDS16(src, LB + buf*8192 + rc*512);
    }
}

__device__ __forceinline__ void mfma8(const short8* Ab, const short8* Bb,
                                      floatx4* acc, int rgrp, int colhalf,
                                      int cl, int kh)
{
    short8 af = Ab[rgrp*64 + cl*4 + kh];
    #pragma unroll
    for (int n = 0; n < 8; n++) {
        short8 bf = Bb[(colhalf*8 + n)*64 + cl*4 + kh];
        acc[n] = __builtin_amdgcn_mfma_f32_16x16x32_bf16(af, bf, acc[n], 0, 0, 0);
    }
}

// ---------------- fused layer tail, BM=64, 512 threads, 3-deep pipeline ----------------
// Wo + res + LN1 + FFN1(relu) + FFN2 + res + LN2 (+ optional next-layer k|v proj).
// 8 waves: rgrp = w&3 (16-row group of 64 rows), colhalf = w>>2 (128-col half).
__global__ __launch_bounds__(512, 2)
void layer_tail(const __hip_bfloat16* __restrict__ vbuf,  // [NTOK,256]
                const __hip_bfloat16* __restrict__ obuf,  // [BATCH,256] o_last rows
                const __hip_bfloat16* __restrict__ Wo,    // [256,256]
                const float* __restrict__ bo,
                const float* __restrict__ g1, const float* __restrict__ b1ln,
                const __hip_bfloat16* __restrict__ W1,    // [1024,256]
                const float* __restrict__ b1f,
                const __hip_bfloat16* __restrict__ W2,    // [256,1024]
                const float* __restrict__ b2f,
                const float* __restrict__ g2, const float* __restrict__ b2ln,
                __hip_bfloat16* __restrict__ xb16,        // in/out [NTOK,256]
                const __hip_bfloat16* __restrict__ Wkv,   // [512,256] next-layer k|v rows, or null
                const float* __restrict__ bk,
                const float* __restrict__ bv2,
                __hip_bfloat16* __restrict__ kout,
                __hip_bfloat16* __restrict__ vout)
{
    // LDS (shorts): LB 3x8192 | LA 3x2048 | X1 16384 | HC 16384 = 63488 (124 KB)
    __shared__ __hip_bfloat16 SM[63488];
    __hip_bfloat16* LB = SM;
    __hip_bfloat16* LA = SM + 24576;
    __hip_bfloat16* X1 = SM + 30720;
    __hip_bfloat16* HC = SM + 47104;
    float* RED = (float*)LA;                              // 256 floats, post-K-loop

    const int bm   = blockIdx.x*64;
    const int tid  = threadIdx.x;
    const int lane = tid & 63;
    const int w    = tid >> 6;        // 0..7
    const int rgrp = w & 3;
    const int colhalf = w >> 2;
    const int cl   = lane & 15;
    const int rg   = lane >> 4;
    const int kh   = rg;

    // ---- Phase 1: C1 = o @ Wo^T ;  x1 = LN1(x + C1 + bo) -> X1 (LDS) ----
    floatx4 acc[8] = {};
    const __hip_bfloat16* asrc = nullptr;
    if (w >= 4) {
        int a = w - 4;
        int grow = bm + a*16 + (lane >> 2);
        bool isl = (grow & (SEQ-1)) == (SEQ-1);
        asrc = (isl ? obuf + (size_t)(grow >> 9)*EMB
                    : vbuf + (size_t)grow*EMB) + (lane & 3)*8;
    }
    stageB64(Wo, 256, 0, 0, LB, 0, w, lane);
    if (w >= 4) GLOAD_LDS16(asrc, LA + (w-4)*512);
    stageB64(Wo, 256, 0, 32, LB, 1, w, lane);
    if (w >= 4) GLOAD_LDS16(asrc + 32, LA + 2048 + (w-4)*512);
    for (int t = 0; t < 8; t++) {
        const int cur = t % 3;
        if (t + 2 < 8) {
            const int nb = (t+2) % 3;
            stageB64(Wo, 256, 0, (t+2)*32, LB, nb, w, lane);
            if (w >= 4) GLOAD_LDS16(asrc + (t+2)*32, LA + nb*2048 + (w-4)*512);
        }
        if (w >= 4) { if (t < 6) WAITCNT(6); else if (t == 6) WAITCNT(3); else WAITCNT(0); }
        else        { if (t < 6) WAITCNT(4); else if (t == 6) WAITCNT(2); else WAITCNT(0); }
        __builtin_amdgcn_s_barrier();
        mfma8((const short8*)(LA + cur*2048), (const short8*)(LB + cur*8192),
              acc, rgrp, colhalf, cl, kh);
        __builtin_amdgcn_s_barrier();
    }
    // epilogue 1
    {
        float gv[8], bbv[8], bv[8];
        #pragma unroll
        for (int n = 0; n < 8; n++) {
            int col = colhalf*128 + n*16 + cl;
            bv[n] = bo[col]; gv[n] = g1[col]; bbv[n] = b1ln[col];
        }
        #pragma unroll
        for (int r = 0; r < 4; r++) {
            int row = bm + rgrp*16 + rg*4 + r;
            const __hip_bfloat16* xr = xb16 + (size_t)row*EMB + colhalf*128;
            float S = 0.f, Q = 0.f;
            #pragma unroll
            for (int n = 0; n < 8; n++) {
                float v = acc[n][r] + bv[n] + __bfloat162float(xr[n*16 + cl]);
                acc[n][r] = v; S += v; Q += v*v;
            }
            #pragma unroll
            for (int o = 1; o < 16; o <<= 1) { S += __shfl_xor(S, o); Q += __shfl_xor(Q, o); }
            if (cl == 0) {
                int idx = rgrp*16 + rg*4 + r;
                RED[colhalf*64 + idx] = S;
                RED[128 + colhalf*64 + idx] = Q;
            }
        }
        __syncthreads();
        #pragma unroll
        for (int r = 0; r < 4; r++) {
            int idx = rgrp*16 + rg*4 + r;
            float S = RED[idx] + RED[64 + idx];
            float Q = RED[128 + idx] + RED[192 + idx];
            float mean = S * (1.f/EMB);
            float var  = Q * (1.f/EMB) - mean*mean;
            float rstd = 1.f / sqrtf(var + 1e-5f);
            #pragma unroll
            for (int n = 0; n < 8; n++) {
                int col = colhalf*128 + n*16 + cl;
                float v = (acc[n][r] - mean)*rstd*gv[n] + bbv[n];
                X1[(col >> 5)*2048 + rgrp*512 + (rg*4 + r)*32 + (col & 31)] = __float2bfloat16(v);
            }
        }
        __syncthreads();
    }

    // ---- Phases 2+3 per 256-col chunk c: h_c = relu(x1 @ W1_c^T + b1) ; acc2 += h_c @ W2_c^T ----
    floatx4 acc2[8] = {};
    for (int c = 0; c < 4; c++) {
        floatx4 fa[8] = {};
        stageB64(W1, 256, c*256, 0, LB, 0, w, lane);
        stageB64(W1, 256, c*256, 32, LB, 1, w, lane);
        for (int t = 0; t < 8; t++) {
            const int cur = t % 3;
            if (t + 2 < 8) stageB64(W1, 256, c*256, (t+2)*32, LB, (t+2)%3, w, lane);
            if (t < 6) WAITCNT(4); else if (t == 6) WAITCNT(2); else WAITCNT(0);
            __builtin_amdgcn_s_barrier();
            mfma8((const short8*)X1 + t*256, (const short8*)(LB + cur*8192),
                  fa, rgrp, colhalf, cl, kh);
            __builtin_amdgcn_s_barrier();
        }
        #pragma unroll
        for (int n = 0; n < 8; n++) {
            int colh = colhalf*128 + n*16 + cl;
            float bb = b1f[c*256 + colh];
            #pragma unroll
            for (int r = 0; r < 4; r++) {
                float v = fmaxf(fa[n][r] + bb, 0.f);
                HC[(colh >> 5)*2048 + rgrp*512 + (rg*4 + r)*32 + (colh & 31)] = __float2bfloat16(v);
            }
        }
        __syncthreads();
        stageB64(W2, 1024, 0, c*256, LB, 0, w, lane);
        stageB64(W2, 1024, 0, c*256 + 32, LB, 1, w, lane);
        for (int t = 0; t < 8; t++) {
            const int cur = t % 3;
            if (t + 2 < 8) stageB64(W2, 1024, 0, c*256 + (t+2)*32, LB, (t+2)%3, w, lane);
            if (t < 6) WAITCNT(4); else if (t == 6) WAITCNT(2); else WAITCNT(0);
            __builtin_amdgcn_s_barrier();
            mfma8((const short8*)HC + t*256, (const short8*)(LB + cur*8192),
                  acc2, rgrp, colhalf, cl, kh);
            __builtin_amdgcn_s_barrier();
        }
    }

    // ---- epilogue 2: x = LN2(x1 + acc2 + b2); chunk new x into HC for phase 4 ----
    {
        float gv[8], bbv[8], bv[8];
        #pragma unroll
        for (int n = 0; n < 8; n++) {
            int col = colhalf*128 + n*16 + cl;
            bv[n] = b2f[col]; gv[n] = g2[col]; bbv[n] = b2ln[col];
        }
        #pragma unroll
        for (int r = 0; r < 4; r++) {
            float S = 0.f, Q = 0.f;
            #pragma unroll
            for (int n = 0; n < 8; n++) {
                int col = colhalf*128 + n*16 + cl;
                float x1v = __bfloat162float(X1[(col >> 5)*2048 + rgrp*512 + (rg*4 + r)*32 + (col & 31)]);
                float v = acc2[n][r] + bv[n] + x1v;
                acc2[n][r] = v; S += v; Q += v*v;
            }
            #pragma unroll
            for (int o = 1; o < 16; o <<= 1) { S += __shfl_xor(S, o); Q += __shfl_xor(Q, o); }
            if (cl == 0) {
                int idx = rgrp*16 + rg*4 + r;
                RED[colhalf*64 + idx] = S;
                RED[128 + colhalf*64 + idx] = Q;
            }
        }
        __syncthreads();
        #pragma unroll
        for (int r = 0; r < 4; r++) {
            int idx = rgrp*16 + rg*4 + r;
            int row = bm + idx;
            float S = RED[idx] + RED[64 + idx];
            float Q = RED[128 + idx] + RED[192 + idx];
            float mean = S * (1.f/EMB);
            float var  = Q * (1.f/EMB) - mean*mean;
            float rstd = 1.f / sqrtf(var + 1e-5f);
            __hip_bfloat16* xr = xb16 + (size_t)row*EMB + colhalf*128;
            #pragma unroll
            for (int n = 0; n < 8; n++) {
                int col = colhalf*128 + n*16 + cl;
                float v = (acc2[n][r] - mean)*rstd*gv[n] + bbv[n];
                __hip_bfloat16 hv = __float2bfloat16(v);
                xr[n*16 + cl] = hv;
                HC[(col >> 5)*2048 + rgrp*512 + (rg*4 + r)*32 + (col & 31)] = hv;
            }
        }
        __syncthreads();
    }

    // ---- Phase 4 (optional): next-layer k|v = x @ Wkv^T + b ----
    if (Wkv != nullptr) {
        #pragma unroll
        for (int nh = 0; nh < 2; nh++) {
            floatx4 a3[8] = {};
            const float* bkv = (nh == 0) ? bk : bv2;
            __hip_bfloat16* dst = (nh == 0) ? kout : vout;
            stageB64(Wkv, 256, nh*256, 0, LB, 0, w, lane);
            stageB64(Wkv, 256, nh*256, 32, LB, 1, w, lane);
            for (int t = 0; t < 8; t++) {
                const int cur = t % 3;
                if (t + 2 < 8) stageB64(Wkv, 256, nh*256, (t+2)*32, LB, (t+2)%3, w, lane);
                if (t < 6) WAITCNT(4); else if (t == 6) WAITCNT(2); else WAITCNT(0);
                __builtin_amdgcn_s_barrier();
                mfma8((const short8*)HC + t*256, (const short8*)(LB + cur*8192),
                      a3, rgrp, colhalf, cl, kh);
                __builtin_amdgcn_s_barrier();
            }
            #pragma unroll
            for (int n = 0; n < 8; n++) {
                int col = colhalf*128 + n*16 + cl;
                float bb = bkv[col];
                #pragma unroll
                for (int r = 0; r < 4; r++) {
                    int row = bm + rgrp*16 + rg*4 + r;
                    dst[(size_t)row*EMB + col] = __float2bfloat16(a3[n][r] + bb);
                }
            }
        }
    }
}

// ---------------- fused fp32 -> bf16 weight conversion (all 4 arrays, 1 launch) ----------------
__global__ void f2b_all(const float* __restrict__ s0, const float* __restrict__ s1,
                        const float* __restrict__ s2, const float* __restrict__ s3,
                        __hip_bfloat16* __restrict__ d0, __hip_bfloat16* __restrict__ d1,
                        __hip_bfloat16* __restrict__ d2, __hip_bfloat16* __restrict__ d3)
{
    int blk = blockIdx.x;
    const float* s; __hip_bfloat16* d; int base;
    if      (blk <  768) { s = s0; d = d0; base = blk; }
    else if (blk < 1024) { s = s1; d = d1; base = blk - 768; }
    else if (blk < 2048) { s = s2; d = d2; base = blk - 1024; }
    else                 { s = s3; d = d3; base = blk - 2048; }
    int i = (base*256 + threadIdx.x)*4;
    float4 v = *(const float4*)(s + i);
    __hip_bfloat16 tmp[4];
    tmp[0] = __float2bfloat16(v.x); tmp[1] = __float2bfloat16(v.y);
    tmp[2] = __float2bfloat16(v.z); tmp[3] = __float2bfloat16(v.w);
    *(ushort4*)(d + i) = *(const ushort4*)tmp;
}

// ---------------- embed + scale + pos-enc; writes bf16 x ----------------
__global__ void embed_kernel(const float* __restrict__ src,
                             const float* __restrict__ emb_W,
                             const float* __restrict__ emb_b,
                             __hip_bfloat16* __restrict__ xb)
{
    int row = blockIdx.x;
    int e = threadIdx.x;
    int s = row % SEQ;
    const float* sr = src + (size_t)row*DIN;
    float acc = emb_b[e];
    #pragma unroll
    for (int d = 0; d < DIN; d++) acc += sr[d]*emb_W[e*DIN + d];
    acc *= 16.0f;                    // sqrt(EMB)
    int i2 = e & ~1;
    float div = expf(-(float)i2 * (9.210340371976184f / (float)EMB));
    float ang = (float)s * div;
    float pe = (e & 1) ? cosf(ang) : sinf(ang);
    xb[(size_t)row*EMB + e] = __float2bfloat16(acc + pe);
}

// ---------------- per-(b,h) last-row attention; o_last -> obuf ----------------
__global__ __launch_bounds__(512)
void attn_last_head(const __hip_bfloat16* __restrict__ xb,   // [NTOK, EMB] bf16
                    const __hip_bfloat16* __restrict__ Wq,   // [EMB, EMB] bf16 (q rows)
                    const float* __restrict__ bq,
                    const __hip_bfloat16* __restrict__ kbuf, // [B*S,256]
                    const __hip_bfloat16* __restrict__ vbuf, // [B*S,256]
                    __hip_bfloat16* __restrict__ obuf,       // [B,256]
                    float* __restrict__ amh)                 // [B*H, SEQ] for this layer
{
    const int h = blockIdx.x, b = blockIdx.y;
    const int t = threadIdx.x;                 // 0..511
    __shared__ float xlast[EMB];
    __shared__ float qpart[HDIM][17];
    __shared__ float qh[HDIM];
    __shared__ float sc[SEQ];
    __shared__ float red1[8], red2[8];
    __shared__ float opart[16][HDIM];

    if (t < EMB) xlast[t] = __bfloat162float(xb[((size_t)b*SEQ + SEQ-1)*EMB + t]);
    __syncthreads();

    {
        int d = t & 31, c = t >> 5;            // c in 0..15
        const __hip_bfloat16* wr = Wq + (size_t)(h*HDIM + d)*EMB + c*16;
        short8 w0 = *(const short8*)(wr);
        short8 w1 = *(const short8*)(wr + 8);
        float p = 0.f;
        #pragma unroll
        for (int j = 0; j < 8; j++)
            p += xlast[c*16 + j]*__bfloat162float(((const __hip_bfloat16*)&w0)[j]);
        #pragma unroll
        for (int j = 0; j < 8; j++)
            p += xlast[c*16 + 8 + j]*__bfloat162float(((const __hip_bfloat16*)&w1)[j]);
        qpart[d][c] = p;
    }
    __syncthreads();
    if (t < HDIM) {
        float qv = bq[h*HDIM + t];
        #pragma unroll
        for (int c = 0; c < 16; c++) qv += qpart[t][c];
        qh[t] = qv;
    }
    __syncthreads();

    {
        const __hip_bfloat16* krow = kbuf + ((size_t)b*SEQ + t)*EMB + h*HDIM;
        float s = 0.f;
        #pragma unroll
        for (int vv = 0; vv < 4; vv++) {
            short8 kk = *(const short8*)(krow + vv*8);
            #pragma unroll
            for (int j = 0; j < 8; j++)
                s += qh[vv*8 + j]*__bfloat162float(((const __hip_bfloat16*)&kk)[j]);
        }
        s *= 0.17677669529663687f;
        if (t == SEQ-1) s += -1e9f;
        sc[t] = s;
    }
    __syncthreads();

    {
        int wv = t >> 6, lane = t & 63;
        float m = sc[t];
        #pragma unroll
        for (int o = 32; o; o >>= 1) m = fmaxf(m, __shfl_xor(m, o));
        if (lane == 0) red1[wv] = m;
        __syncthreads();
        m = red1[0];
        #pragma unroll
        for (int i = 1; i < 8; i++) m = fmaxf(m, red1[i]);
        float e = expf(sc[t] - m);
        float s = e;
        #pragma unroll
        for (int o = 32; o; o >>= 1) s += __shfl_xor(s, o);
        if (lane == 0) red2[wv] = s;
        __syncthreads();
        float tot = red2[0]+red2[1]+red2[2]+red2[3]+red2[4]+red2[5]+red2[6]+red2[7];
        float a = e / tot;
        sc[t] = a;
        amh[((size_t)b*NHEADS + h)*SEQ + t] = a;
    }
    __syncthreads();

    {
        int e = t & 31, part = t >> 5;
        float o = 0.f;
        const __hip_bfloat16* vc = vbuf + (size_t)b*SEQ*EMB + h*HDIM + e;
        for (int k = part*32; k < part*32 + 32; k++)
            o += sc[k]*__bfloat162float(vc[(size_t)k*EMB]);
        opart[part][e] = o;
    }
    __syncthreads();
    if (t < HDIM) {
        float o = 0.f;
        #pragma unroll
        for (int p = 0; p < 16; p++) o += opart[p][t];
        obuf[b*EMB + h*HDIM + t] = __float2bfloat16(o);
    }
}

// ---------------- write full attns output [L,B,S,S]; head-avg fused for last rows ----------------
__global__ void write_attns(float* __restrict__ attns, const float* __restrict__ amh_all)
{
    constexpr int PER_ROW = SEQ/4;
    size_t tid = (size_t)blockIdx.x*blockDim.x + threadIdx.x;
    size_t row = tid / PER_ROW;
    int c4 = (int)(tid % PER_ROW);
    int q = (int)(row % SEQ);
    float4 v = make_float4(0.f,0.f,0.f,0.f);
    if (q == SEQ-1) {
        size_t lb = row / SEQ;
        const float* base = amh_all + lb*NHEADS*SEQ + c4*4;
        float x0=0.f, x1=0.f, x2=0.f, x3=0.f;
        #pragma unroll
        for (int h = 0; h < NHEADS; h++) {
            const float* r = base + (size_t)h*SEQ;
            x0 += r[0]; x1 += r[1]; x2 += r[2]; x3 += r[3];
        }
        v = make_float4(x0*0.125f, x1*0.125f, x2*0.125f, x3*0.125f);
    } else if ((q >> 2) == c4) {
        ((float*)&v)[q & 3] = 1.f;
    }
    ((float4*)attns)[tid] = v;
}

// ---------------- fused relu-sum over sequence + decode + log_softmax ----------------
__global__ __launch_bounds__(512)
void decode_fused(const __hip_bfloat16* __restrict__ xb, const float* __restrict__ dec_W,
                  float* __restrict__ out)
{
    int b = blockIdx.x, t = threadIdx.x;
    int e = t & 255, half = t >> 8;
    __shared__ float rs[2][256];
    {
        const __hip_bfloat16* xp = xb + ((size_t)b*SEQ + half*256)*EMB + e;
        float r = 0.f;
        for (int i = 0; i < 256; i++) r += fmaxf(__bfloat162float(xp[(size_t)i*EMB]), 0.f);
        rs[half][e] = r;
    }
    __syncthreads();
    float part[NCLS];
    if (t < 256) {
        float rr = rs[0][t] + rs[1][t];
        #pragma unroll
        for (int c = 0; c < NCLS; c++) part[c] = rr * dec_W[c*EMB + t];
    } else {
        #pragma unroll
        for (int c = 0; c < NCLS; c++) part[c] = 0.f;
    }
    #pragma unroll
    for (int o = 32; o; o >>= 1)
        #pragma unroll
        for (int c = 0; c < NCLS; c++) part[c] += __shfl_xor(part[c], o);
    __shared__ float red[8][NCLS];
    int wv = t >> 6, lane = t & 63;
    if (lane == 0)
        #pragma unroll
        for (int c = 0; c < NCLS; c++) red[wv][c] = part[c];
    __syncthreads();
    if (t == 0) {
        float lg[NCLS];
        float m = -1e30f;
        #pragma unroll
        for (int c = 0; c < NCLS; c++) {
            float s = 0.f;
            #pragma unroll
            for (int wvi = 0; wvi < 8; wvi++) s += red[wvi][c];
            lg[c] = s * (1.f/(float)SEQ);
            m = fmaxf(m, lg[c]);
        }
        float s = 0.f;
        #pragma unroll
        for (int c = 0; c < NCLS; c++) s += expf(lg[c] - m);
        float ls = logf(s);
        #pragma unroll
        for (int c = 0; c < NCLS; c++) out[b*NCLS + c] = lg[c] - m - ls;
    }
}

} // namespace

extern "C" void kernel_launch(void* const* d_in, const int* in_sizes, int n_in,
                              void* d_out, int out_size, void* d_ws, size_t ws_size,
                              hipStream_t stream)
{
    const float* src   = (const float*)d_in[0];
    const float* emb_W = (const float*)d_in[1];
    const float* emb_b = (const float*)d_in[2];
    const float* Wqkv  = (const float*)d_in[3];
    const float* bqkv  = (const float*)d_in[4];
    const float* Wo    = (const float*)d_in[5];
    const float* bo    = (const float*)d_in[6];
    const float* ln1_g = (const float*)d_in[7];
    const float* ln1_b = (const float*)d_in[8];
    const float* ln2_g = (const float*)d_in[9];
    const float* ln2_b = (const float*)d_in[10];
    const float* W1    = (const float*)d_in[11];
    const float* b1    = (const float*)d_in[12];
    const float* W2    = (const float*)d_in[13];
    const float* b2    = (const float*)d_in[14];
    const float* dec_W = (const float*)d_in[15];

    float* out   = (float*)d_out;               // [32,10]
    float* attns = out + BATCH*NCLS;            // [4,32,512,512]

    // workspace layout (~35 MB)
    char* ws = (char*)d_ws;
    __hip_bfloat16* xb16 = (__hip_bfloat16*)ws;     ws += (size_t)NTOK*EMB*2;     //  8.39 MB
    __hip_bfloat16* kbuf = (__hip_bfloat16*)ws;     ws += (size_t)NTOK*EMB*2;     //  8.39 MB
    __hip_bfloat16* vbuf = (__hip_bfloat16*)ws;     ws += (size_t)NTOK*EMB*2;     //  8.39 MB
    __hip_bfloat16* obuf = (__hip_bfloat16*)ws;     ws += (size_t)BATCH*EMB*2;
    __hip_bfloat16* wq16 = (__hip_bfloat16*)ws;     ws += (size_t)NLAYER*3*EMB*EMB*2;
    __hip_bfloat16* wo16 = (__hip_bfloat16*)ws;     ws += (size_t)NLAYER*EMB*EMB*2;
    __hip_bfloat16* w116 = (__hip_bfloat16*)ws;     ws += (size_t)NLAYER*FF*EMB*2;
    __hip_bfloat16* w216 = (__hip_bfloat16*)ws;     ws += (size_t)NLAYER*EMB*FF*2;
    float*          amall= (float*)ws;              ws += (size_t)NLAYER*BATCH*NHEADS*SEQ*4; // 2.1 MB

    // weight conversion fp32 -> bf16 (single launch)
    f2b_all<<<3072, 256, 0, stream>>>(Wqkv, Wo, W1, W2, wq16, wo16, w116, w216);

    embed_kernel<<<NTOK, EMB, 0, stream>>>(src, emb_W, emb_b, xb16);

    // layer-0 k|v projection (subsequent layers' kv fused into layer_tail)
    gemm_mfma<false, true><<<dim3(512/128, NTOK/128), 256, 0, stream>>>(
        xb16, EMB, wq16 + (size_t)EMB*EMB, bqkv + EMB, kbuf, vbuf, EMB, EMB);

    for (int l = 0; l < NLAYER; l++) {
        const __hip_bfloat16* wql = wq16 + (size_t)l*3*EMB*EMB;
        const float* bql = bqkv + (size_t)l*3*EMB;

        // fused per-(b,h): q GEMV + scores + softmax + per-head row + o_last -> obuf
        attn_last_head<<<dim3(NHEADS, BATCH), 512, 0, stream>>>(
            xb16, wql, bql, kbuf, vbuf, obuf, amall + (size_t)l*BATCH*NHEADS*SEQ);

        // fused tail: Wo + res + LN1 + FFN1 + FFN2 + res + LN2 (+ next-layer kv)
        const bool last = (l == NLAYER-1);
        const __hip_bfloat16* wkv_next = last ? nullptr
            : wq16 + (size_t)(l+1)*3*EMB*EMB + (size_t)EMB*EMB;
        const float* bk_next = last ? nullptr : bqkv + (size_t)(l+1)*3*EMB + EMB;
        const float* bv_next = last ? nullptr : bqkv + (size_t)(l+1)*3*EMB + 2*EMB;
        layer_tail<<<NTOK/64, 512, 0, stream>>>(
            vbuf, obuf,
            wo16 + (size_t)l*EMB*EMB, bo + (size_t)l*EMB,
            ln1_g + l*EMB, ln1_b + l*EMB,
            w116 + (size_t)l*FF*EMB, b1 + (size_t)l*FF,
            w216 + (size_t)l*EMB*FF, b2 + (size_t)l*EMB,
            ln2_g + l*EMB, ln2_b + l*EMB,
            xb16,
            wkv_next, bk_next, bv_next,
            last ? nullptr : kbuf, last ? nullptr : vbuf);
    }

    {
        size_t total_f4 = (size_t)NLAYER*BATCH*SEQ*(SEQ/4);
        int blocks = (int)((total_f4 + 255)/256);
        write_attns<<<blocks, 256, 0, stream>>>(attns, amall);
    }

    decode_fused<<<BATCH, 512, 0, stream>>>(xb16, dec_W, out);
}

// Round 15
// 442.147 us; speedup vs baseline: 1.2578x; 1.0053x over previous
//
#include <hip/hip_runtime.h>
#include <hip/hip_bf16.h>
#include <math.h>

namespace {

constexpr int BATCH = 32;
constexpr int SEQ   = 512;
constexpr int DIN   = 9;
constexpr int EMB   = 256;
constexpr int FF    = 1024;
constexpr int NLAYER= 4;
constexpr int NCLS  = 10;
constexpr int NHEADS= 8;
constexpr int HDIM  = 32;
constexpr int NTOK  = BATCH*SEQ;      // 16384

typedef __attribute__((ext_vector_type(8))) short short8;
typedef __attribute__((ext_vector_type(4))) float floatx4;

#define GLOAD_LDS16(g, l) __builtin_amdgcn_global_load_lds( \
    (const __attribute__((address_space(1))) unsigned*)(g), \
    (__attribute__((address_space(3))) unsigned*)(l), 16, 0, 0)

#define WAITCNT(N) asm volatile("s_waitcnt vmcnt(" #N ")" ::: "memory")

// ---------------- shared helpers (BM=64, 8 waves) ----------------
// stage a 256-row x 32-k B slab: 16 chunks of 1KB, 2 per wave
__device__ __forceinline__ void stageB64(const __hip_bfloat16* __restrict__ W, int ldw,
                                         int rowbase, int kbase,
                                         __hip_bfloat16* LB, int buf, int w, int lane)
{
    #pragma unroll
    for (int i = 0; i < 2; i++) {
        int rc = 2*w + i;
        const __hip_bfloat16* src = W + (size_t)(rowbase + rc*16 + (lane >> 2))*ldw
                                      + kbase + (lane & 3)*8;
        GLOAD_LDS16(src, LB + buf*8192 + rc*512);
    }
}

__device__ __forceinline__ void mfma8(const short8* Ab, const short8* Bb,
                                      floatx4* acc, int rgrp, int colhalf,
                                      int cl, int kh)
{
    short8 af = Ab[rgrp*64 + cl*4 + kh];
    #pragma unroll
    for (int n = 0; n < 8; n++) {
        short8 bf = Bb[(colhalf*8 + n)*64 + cl*4 + kh];
        acc[n] = __builtin_amdgcn_mfma_f32_16x16x32_bf16(af, bf, acc[n], 0, 0, 0);
    }
}

// ---------------- fused layer tail, BM=64, 512 threads, 4-buf single-barrier pipeline ----------------
// Wo + res + LN1 + FFN1(relu) + FFN2 + res + LN2 (+ optional next-layer k|v proj).
// 8 waves: rgrp = w&3 (16-row group), colhalf = w>>2 (128-col half).
// 4 LDS buffers + prefetch distance 2 -> ONE barrier per K-step is race-free:
// stage target (t+2)&3 differs from every buffer readable by a wave within
// one-iteration skew (barrier bounds skew; reads of (t+2)&3 completed before
// barrier t-1 which the staging wave has passed).
__global__ __launch_bounds__(512, 2)
void layer_tail(const __hip_bfloat16* __restrict__ vbuf,  // [NTOK,256]
                const __hip_bfloat16* __restrict__ obuf,  // [BATCH,256] o_last rows
                const __hip_bfloat16* __restrict__ Wo,    // [256,256]
                const float* __restrict__ bo,
                const float* __restrict__ g1, const float* __restrict__ b1ln,
                const __hip_bfloat16* __restrict__ W1,    // [1024,256]
                const float* __restrict__ b1f,
                const __hip_bfloat16* __restrict__ W2,    // [256,1024]
                const float* __restrict__ b2f,
                const float* __restrict__ g2, const float* __restrict__ b2ln,
                __hip_bfloat16* __restrict__ xb16,        // in/out [NTOK,256]
                const __hip_bfloat16* __restrict__ Wkv,   // [512,256] next-layer k|v rows, or null
                const float* __restrict__ bk,
                const float* __restrict__ bv2,
                __hip_bfloat16* __restrict__ kout,
                __hip_bfloat16* __restrict__ vout)
{
    // LDS (shorts): LB 4x8192 | LA 4x2048 | X1 16384 | HC 16384 = 73728 (144 KB)
    __shared__ __hip_bfloat16 SM[73728];
    __hip_bfloat16* LB = SM;
    __hip_bfloat16* LA = SM + 32768;
    __hip_bfloat16* X1 = SM + 40960;
    __hip_bfloat16* HC = SM + 57344;
    float* RED = (float*)LA;                              // 256 floats, post-K-loop

    const int bm   = blockIdx.x*64;
    const int tid  = threadIdx.x;
    const int lane = tid & 63;
    const int w    = tid >> 6;        // 0..7
    const int rgrp = w & 3;
    const int colhalf = w >> 2;
    const int cl   = lane & 15;
    const int rg   = lane >> 4;
    const int kh   = rg;

    // ---- Phase 1: C1 = o @ Wo^T ;  x1 = LN1(x + C1 + bo) -> X1 (LDS) ----
    floatx4 acc[8] = {};
    const __hip_bfloat16* asrc = nullptr;
    if (w >= 4) {
        int a = w - 4;
        int grow = bm + a*16 + (lane >> 2);
        bool isl = (grow & (SEQ-1)) == (SEQ-1);
        asrc = (isl ? obuf + (size_t)(grow >> 9)*EMB
                    : vbuf + (size_t)grow*EMB) + (lane & 3)*8;
    }
    stageB64(Wo, 256, 0, 0, LB, 0, w, lane);
    if (w >= 4) GLOAD_LDS16(asrc, LA + (w-4)*512);
    stageB64(Wo, 256, 0, 32, LB, 1, w, lane);
    if (w >= 4) GLOAD_LDS16(asrc + 32, LA + 2048 + (w-4)*512);
    for (int t = 0; t < 8; t++) {
        const int cur = t & 3;
        if (t + 2 < 8) {
            const int nb = (t+2) & 3;
            stageB64(Wo, 256, 0, (t+2)*32, LB, nb, w, lane);
            if (w >= 4) GLOAD_LDS16(asrc + (t+2)*32, LA + nb*2048 + (w-4)*512);
        }
        if (w >= 4) { if (t < 6) WAITCNT(6); else if (t == 6) WAITCNT(3); else WAITCNT(0); }
        else        { if (t < 6) WAITCNT(4); else if (t == 6) WAITCNT(2); else WAITCNT(0); }
        __builtin_amdgcn_s_barrier();
        mfma8((const short8*)(LA + cur*2048), (const short8*)(LB + cur*8192),
              acc, rgrp, colhalf, cl, kh);
    }
    // epilogue 1
    {
        float gv[8], bbv[8], bv[8];
        #pragma unroll
        for (int n = 0; n < 8; n++) {
            int col = colhalf*128 + n*16 + cl;
            bv[n] = bo[col]; gv[n] = g1[col]; bbv[n] = b1ln[col];
        }
        #pragma unroll
        for (int r = 0; r < 4; r++) {
            int row = bm + rgrp*16 + rg*4 + r;
            const __hip_bfloat16* xr = xb16 + (size_t)row*EMB + colhalf*128;
            float S = 0.f, Q = 0.f;
            #pragma unroll
            for (int n = 0; n < 8; n++) {
                float v = acc[n][r] + bv[n] + __bfloat162float(xr[n*16 + cl]);
                acc[n][r] = v; S += v; Q += v*v;
            }
            #pragma unroll
            for (int o = 1; o < 16; o <<= 1) { S += __shfl_xor(S, o); Q += __shfl_xor(Q, o); }
            if (cl == 0) {
                int idx = rgrp*16 + rg*4 + r;
                RED[colhalf*64 + idx] = S;
                RED[128 + colhalf*64 + idx] = Q;
            }
        }
        __syncthreads();
        #pragma unroll
        for (int r = 0; r < 4; r++) {
            int idx = rgrp*16 + rg*4 + r;
            float S = RED[idx] + RED[64 + idx];
            float Q = RED[128 + idx] + RED[192 + idx];
            float mean = S * (1.f/EMB);
            float var  = Q * (1.f/EMB) - mean*mean;
            float rstd = 1.f / sqrtf(var + 1e-5f);
            #pragma unroll
            for (int n = 0; n < 8; n++) {
                int col = colhalf*128 + n*16 + cl;
                float v = (acc[n][r] - mean)*rstd*gv[n] + bbv[n];
                X1[(col >> 5)*2048 + rgrp*512 + (rg*4 + r)*32 + (col & 31)] = __float2bfloat16(v);
            }
        }
        __syncthreads();
    }

    // ---- Phases 2+3 per 256-col chunk c: h_c = relu(x1 @ W1_c^T + b1) ; acc2 += h_c @ W2_c^T ----
    floatx4 acc2[8] = {};
    for (int c = 0; c < 4; c++) {
        floatx4 fa[8] = {};
        stageB64(W1, 256, c*256, 0, LB, 0, w, lane);
        stageB64(W1, 256, c*256, 32, LB, 1, w, lane);
        for (int t = 0; t < 8; t++) {
            const int cur = t & 3;
            if (t + 2 < 8) stageB64(W1, 256, c*256, (t+2)*32, LB, (t+2)&3, w, lane);
            if (t < 6) WAITCNT(4); else if (t == 6) WAITCNT(2); else WAITCNT(0);
            __builtin_amdgcn_s_barrier();
            mfma8((const short8*)X1 + t*256, (const short8*)(LB + cur*8192),
                  fa, rgrp, colhalf, cl, kh);
        }
        #pragma unroll
        for (int n = 0; n < 8; n++) {
            int colh = colhalf*128 + n*16 + cl;
            float bb = b1f[c*256 + colh];
            #pragma unroll
            for (int r = 0; r < 4; r++) {
                float v = fmaxf(fa[n][r] + bb, 0.f);
                HC[(colh >> 5)*2048 + rgrp*512 + (rg*4 + r)*32 + (colh & 31)] = __float2bfloat16(v);
            }
        }
        __syncthreads();
        stageB64(W2, 1024, 0, c*256, LB, 0, w, lane);
        stageB64(W2, 1024, 0, c*256 + 32, LB, 1, w, lane);
        for (int t = 0; t < 8; t++) {
            const int cur = t & 3;
            if (t + 2 < 8) stageB64(W2, 1024, 0, c*256 + (t+2)*32, LB, (t+2)&3, w, lane);
            if (t < 6) WAITCNT(4); else if (t == 6) WAITCNT(2); else WAITCNT(0);
            __builtin_amdgcn_s_barrier();
            mfma8((const short8*)HC + t*256, (const short8*)(LB + cur*8192),
                  acc2, rgrp, colhalf, cl, kh);
        }
        __syncthreads();   // all waves done with HC before next chunk overwrites it
    }

    // ---- epilogue 2: x = LN2(x1 + acc2 + b2); chunk new x into HC for phase 4 ----
    {
        float gv[8], bbv[8], bv[8];
        #pragma unroll
        for (int n = 0; n < 8; n++) {
            int col = colhalf*128 + n*16 + cl;
            bv[n] = b2f[col]; gv[n] = g2[col]; bbv[n] = b2ln[col];
        }
        #pragma unroll
        for (int r = 0; r < 4; r++) {
            float S = 0.f, Q = 0.f;
            #pragma unroll
            for (int n = 0; n < 8; n++) {
                int col = colhalf*128 + n*16 + cl;
                float x1v = __bfloat162float(X1[(col >> 5)*2048 + rgrp*512 + (rg*4 + r)*32 + (col & 31)]);
                float v = acc2[n][r] + bv[n] + x1v;
                acc2[n][r] = v; S += v; Q += v*v;
            }
            #pragma unroll
            for (int o = 1; o < 16; o <<= 1) { S += __shfl_xor(S, o); Q += __shfl_xor(Q, o); }
            if (cl == 0) {
                int idx = rgrp*16 + rg*4 + r;
                RED[colhalf*64 + idx] = S;
                RED[128 + colhalf*64 + idx] = Q;
            }
        }
        __syncthreads();
        #pragma unroll
        for (int r = 0; r < 4; r++) {
            int idx = rgrp*16 + rg*4 + r;
            int row = bm + idx;
            float S = RED[idx] + RED[64 + idx];
            float Q = RED[128 + idx] + RED[192 + idx];
            float mean = S * (1.f/EMB);
            float var  = Q * (1.f/EMB) - mean*mean;
            float rstd = 1.f / sqrtf(var + 1e-5f);
            __hip_bfloat16* xr = xb16 + (size_t)row*EMB + colhalf*128;
            #pragma unroll
            for (int n = 0; n < 8; n++) {
                int col = colhalf*128 + n*16 + cl;
                float v = (acc2[n][r] - mean)*rstd*gv[n] + bbv[n];
                __hip_bfloat16 hv = __float2bfloat16(v);
                xr[n*16 + cl] = hv;
                HC[(col >> 5)*2048 + rgrp*512 + (rg*4 + r)*32 + (col & 31)] = hv;
            }
        }
        __syncthreads();
    }

    // ---- Phase 4 (optional): next-layer k|v = x @ Wkv^T + b ----
    if (Wkv != nullptr) {
        #pragma unroll
        for (int nh = 0; nh < 2; nh++) {
            floatx4 a3[8] = {};
            const float* bkv = (nh == 0) ? bk : bv2;
            __hip_bfloat16* dst = (nh == 0) ? kout : vout;
            stageB64(Wkv, 256, nh*256, 0, LB, 0, w, lane);
            stageB64(Wkv, 256, nh*256, 32, LB, 1, w, lane);
            for (int t = 0; t < 8; t++) {
                const int cur = t & 3;
                if (t + 2 < 8) stageB64(Wkv, 256, nh*256, (t+2)*32, LB, (t+2)&3, w, lane);
                if (t < 6) WAITCNT(4); else if (t == 6) WAITCNT(2); else WAITCNT(0);
                __builtin_amdgcn_s_barrier();
                mfma8((const short8*)HC + t*256, (const short8*)(LB + cur*8192),
                      a3, rgrp, colhalf, cl, kh);
            }
            #pragma unroll
            for (int n = 0; n < 8; n++) {
                int col = colhalf*128 + n*16 + cl;
                float bb = bkv[col];
                #pragma unroll
                for (int r = 0; r < 4; r++) {
                    int row = bm + rgrp*16 + rg*4 + r;
                    dst[(size_t)row*EMB + col] = __float2bfloat16(a3[n][r] + bb);
                }
            }
        }
    }
}

// ---------------- fused embed + pos-enc + layer-0 k|v projection ----------------
// 256 blocks x 64 rows, 512 threads. Embedding into chunked LDS A-layout (+xb16
// global), then phase-4-style kv projection. Weight prefetch issued before the
// trig-heavy embed loop to hide L2 latency under VALU.
__global__ __launch_bounds__(512, 2)
void embed_kv(const float* __restrict__ src,
              const float* __restrict__ emb_W,
              const float* __restrict__ emb_b,
              const __hip_bfloat16* __restrict__ Wkv,   // [512,256] k|v rows of Wqkv[0]
              const float* __restrict__ bk,
              const float* __restrict__ bv2,
              __hip_bfloat16* __restrict__ xb16,
              __hip_bfloat16* __restrict__ kout,
              __hip_bfloat16* __restrict__ vout)
{
    __shared__ __hip_bfloat16 SM2[49152];   // LB 4x8192 | XC 16384 = 96 KB
    __hip_bfloat16* LB = SM2;
    __hip_bfloat16* XC = SM2 + 32768;

    const int bm   = blockIdx.x*64;
    const int tid  = threadIdx.x;
    const int lane = tid & 63;
    const int w    = tid >> 6;
    const int rgrp = w & 3;
    const int colhalf = w >> 2;
    const int cl   = lane & 15;
    const int rg   = lane >> 4;
    const int kh   = rg;

    // prefetch first k-weight slabs (hidden under embed compute)
    stageB64(Wkv, 256, 0, 0, LB, 0, w, lane);
    stageB64(Wkv, 256, 0, 32, LB, 1, w, lane);

    // embed: 64 rows x 256 cols, 32 elems/thread (coalesced)
    for (int i = 0; i < 32; i++) {
        int idx = tid + i*512;
        int rr = idx >> 8, e = idx & 255;
        int row = bm + rr;
        int s = row & (SEQ-1);
        const float* sr = src + (size_t)row*DIN;
        float acc = emb_b[e];
        #pragma unroll
        for (int d = 0; d < DIN; d++) acc += sr[d]*emb_W[e*DIN + d];
        acc *= 16.0f;                    // sqrt(EMB)
        int i2 = e & ~1;
        float div = expf(-(float)i2 * (9.210340371976184f / (float)EMB));
        float ang = (float)s * div;
        float pe = (e & 1) ? cosf(ang) : sinf(ang);
        __hip_bfloat16 hv = __float2bfloat16(acc + pe);
        xb16[(size_t)row*EMB + e] = hv;
        XC[(e >> 5)*2048 + rr*32 + (e & 31)] = hv;
    }
    __syncthreads();

    // k|v projection (same as layer_tail phase 4)
    #pragma unroll
    for (int nh = 0; nh < 2; nh++) {
        floatx4 a3[8] = {};
        const float* bkv = (nh == 0) ? bk : bv2;
        __hip_bfloat16* dst = (nh == 0) ? kout : vout;
        if (nh == 1) {
            stageB64(Wkv, 256, 256, 0, LB, 0, w, lane);
            stageB64(Wkv, 256, 256, 32, LB, 1, w, lane);
        }
        for (int t = 0; t < 8; t++) {
            const int cur = t & 3;
            if (t + 2 < 8) stageB64(Wkv, 256, nh*256, (t+2)*32, LB, (t+2)&3, w, lane);
            if (t < 6) WAITCNT(4); else if (t == 6) WAITCNT(2); else WAITCNT(0);
            __builtin_amdgcn_s_barrier();
            mfma8((const short8*)XC + t*256, (const short8*)(LB + cur*8192),
                  a3, rgrp, colhalf, cl, kh);
        }
        #pragma unroll
        for (int n = 0; n < 8; n++) {
            int col = colhalf*128 + n*16 + cl;
            float bb = bkv[col];
            #pragma unroll
            for (int r = 0; r < 4; r++) {
                int row = bm + rgrp*16 + rg*4 + r;
                dst[(size_t)row*EMB + col] = __float2bfloat16(a3[n][r] + bb);
            }
        }
    }
}

// ---------------- fused fp32 -> bf16 weight conversion (all 4 arrays, 1 launch) ----------------
__global__ void f2b_all(const float* __restrict__ s0, const float* __restrict__ s1,
                        const float* __restrict__ s2, const float* __restrict__ s3,
                        __hip_bfloat16* __restrict__ d0, __hip_bfloat16* __restrict__ d1,
                        __hip_bfloat16* __restrict__ d2, __hip_bfloat16* __restrict__ d3)
{
    int blk = blockIdx.x;
    const float* s; __hip_bfloat16* d; int base;
    if      (blk <  768) { s = s0; d = d0; base = blk; }
    else if (blk < 1024) { s = s1; d = d1; base = blk - 768; }
    else if (blk < 2048) { s = s2; d = d2; base = blk - 1024; }
    else                 { s = s3; d = d3; base = blk - 2048; }
    int i = (base*256 + threadIdx.x)*4;
    float4 v = *(const float4*)(s + i);
    __hip_bfloat16 tmp[4];
    tmp[0] = __float2bfloat16(v.x); tmp[1] = __float2bfloat16(v.y);
    tmp[2] = __float2bfloat16(v.z); tmp[3] = __float2bfloat16(v.w);
    *(ushort4*)(d + i) = *(const ushort4*)tmp;
}

// ---------------- per-(b,h) last-row attention; o_last -> obuf ----------------
__global__ __launch_bounds__(512)
void attn_last_head(const __hip_bfloat16* __restrict__ xb,   // [NTOK, EMB] bf16
                    const __hip_bfloat16* __restrict__ Wq,   // [EMB, EMB] bf16 (q rows)
                    const float* __restrict__ bq,
                    const __hip_bfloat16* __restrict__ kbuf, // [B*S,256]
                    const __hip_bfloat16* __restrict__ vbuf, // [B*S,256]
                    __hip_bfloat16* __restrict__ obuf,       // [B,256]
                    float* __restrict__ amh)                 // [B*H, SEQ] for this layer
{
    const int h = blockIdx.x, b = blockIdx.y;
    const int t = threadIdx.x;                 // 0..511
    __shared__ float xlast[EMB];
    __shared__ float qpart[HDIM][17];
    __shared__ float qh[HDIM];
    __shared__ float sc[SEQ];
    __shared__ float red1[8], red2[8];
    __shared__ float opart[16][HDIM];

    if (t < EMB) xlast[t] = __bfloat162float(xb[((size_t)b*SEQ + SEQ-1)*EMB + t]);
    __syncthreads();

    {
        int d = t & 31, c = t >> 5;            // c in 0..15
        const __hip_bfloat16* wr = Wq + (size_t)(h*HDIM + d)*EMB + c*16;
        short8 w0 = *(const short8*)(wr);
        short8 w1 = *(const short8*)(wr + 8);
        float p = 0.f;
        #pragma unroll
        for (int j = 0; j < 8; j++)
            p += xlast[c*16 + j]*__bfloat162float(((const __hip_bfloat16*)&w0)[j]);
        #pragma unroll
        for (int j = 0; j < 8; j++)
            p += xlast[c*16 + 8 + j]*__bfloat162float(((const __hip_bfloat16*)&w1)[j]);
        qpart[d][c] = p;
    }
    __syncthreads();
    if (t < HDIM) {
        float qv = bq[h*HDIM + t];
        #pragma unroll
        for (int c = 0; c < 16; c++) qv += qpart[t][c];
        qh[t] = qv;
    }
    __syncthreads();

    {
        const __hip_bfloat16* krow = kbuf + ((size_t)b*SEQ + t)*EMB + h*HDIM;
        float s = 0.f;
        #pragma unroll
        for (int vv = 0; vv < 4; vv++) {
            short8 kk = *(const short8*)(krow + vv*8);
            #pragma unroll
            for (int j = 0; j < 8; j++)
                s += qh[vv*8 + j]*__bfloat162float(((const __hip_bfloat16*)&kk)[j]);
        }
        s *= 0.17677669529663687f;
        if (t == SEQ-1) s += -1e9f;
        sc[t] = s;
    }
    __syncthreads();

    {
        int wv = t >> 6, lane = t & 63;
        float m = sc[t];
        #pragma unroll
        for (int o = 32; o; o >>= 1) m = fmaxf(m, __shfl_xor(m, o));
        if (lane == 0) red1[wv] = m;
        __syncthreads();
        m = red1[0];
        #pragma unroll
        for (int i = 1; i < 8; i++) m = fmaxf(m, red1[i]);
        float e = expf(sc[t] - m);
        float s = e;
        #pragma unroll
        for (int o = 32; o; o >>= 1) s += __shfl_xor(s, o);
        if (lane == 0) red2[wv] = s;
        __syncthreads();
        float tot = red2[0]+red2[1]+red2[2]+red2[3]+red2[4]+red2[5]+red2[6]+red2[7];
        float a = e / tot;
        sc[t] = a;
        amh[((size_t)b*NHEADS + h)*SEQ + t] = a;
    }
    __syncthreads();

    {
        int e = t & 31, part = t >> 5;
        float o = 0.f;
        const __hip_bfloat16* vc = vbuf + (size_t)b*SEQ*EMB + h*HDIM + e;
        for (int k = part*32; k < part*32 + 32; k++)
            o += sc[k]*__bfloat162float(vc[(size_t)k*EMB]);
        opart[part][e] = o;
    }
    __syncthreads();
    if (t < HDIM) {
        float o = 0.f;
        #pragma unroll
        for (int p = 0; p < 16; p++) o += opart[p][t];
        obuf[b*EMB + h*HDIM + t] = __float2bfloat16(o);
    }
}

// ---------------- write full attns output [L,B,S,S]; head-avg fused for last rows ----------------
__global__ void write_attns(float* __restrict__ attns, const float* __restrict__ amh_all)
{
    constexpr int PER_ROW = SEQ/4;
    size_t tid = (size_t)blockIdx.x*blockDim.x + threadIdx.x;
    size_t row = tid / PER_ROW;
    int c4 = (int)(tid % PER_ROW);
    int q = (int)(row % SEQ);
    float4 v = make_float4(0.f,0.f,0.f,0.f);
    if (q == SEQ-1) {
        size_t lb = row / SEQ;
        const float* base = amh_all + lb*NHEADS*SEQ + c4*4;
        float x0=0.f, x1=0.f, x2=0.f, x3=0.f;
        #pragma unroll
        for (int h = 0; h < NHEADS; h++) {
            const float* r = base + (size_t)h*SEQ;
            x0 += r[0]; x1 += r[1]; x2 += r[2]; x3 += r[3];
        }
        v = make_float4(x0*0.125f, x1*0.125f, x2*0.125f, x3*0.125f);
    } else if ((q >> 2) == c4) {
        ((float*)&v)[q & 3] = 1.f;
    }
    ((float4*)attns)[tid] = v;
}

// ---------------- fused relu-sum over sequence + decode + log_softmax ----------------
__global__ __launch_bounds__(512)
void decode_fused(const __hip_bfloat16* __restrict__ xb, const float* __restrict__ dec_W,
                  float* __restrict__ out)
{
    int b = blockIdx.x, t = threadIdx.x;
    int e = t & 255, half = t >> 8;
    __shared__ float rs[2][256];
    {
        const __hip_bfloat16* xp = xb + ((size_t)b*SEQ + half*256)*EMB + e;
        float r = 0.f;
        for (int i = 0; i < 256; i++) r += fmaxf(__bfloat162float(xp[(size_t)i*EMB]), 0.f);
        rs[half][e] = r;
    }
    __syncthreads();
    float part[NCLS];
    if (t < 256) {
        float rr = rs[0][t] + rs[1][t];
        #pragma unroll
        for (int c = 0; c < NCLS; c++) part[c] = rr * dec_W[c*EMB + t];
    } else {
        #pragma unroll
        for (int c = 0; c < NCLS; c++) part[c] = 0.f;
    }
    #pragma unroll
    for (int o = 32; o; o >>= 1)
        #pragma unroll
        for (int c = 0; c < NCLS; c++) part[c] += __shfl_xor(part[c], o);
    __shared__ float red[8][NCLS];
    int wv = t >> 6, lane = t & 63;
    if (lane == 0)
        #pragma unroll
        for (int c = 0; c < NCLS; c++) red[wv][c] = part[c];
    __syncthreads();
    if (t == 0) {
        float lg[NCLS];
        float m = -1e30f;
        #pragma unroll
        for (int c = 0; c < NCLS; c++) {
            float s = 0.f;
            #pragma unroll
            for (int wvi = 0; wvi < 8; wvi++) s += red[wvi][c];
            lg[c] = s * (1.f/(float)SEQ);
            m = fmaxf(m, lg[c]);
        }
        float s = 0.f;
        #pragma unroll
        for (int c = 0; c < NCLS; c++) s += expf(lg[c] - m);
        float ls = logf(s);
        #pragma unroll
        for (int c = 0; c < NCLS; c++) out[b*NCLS + c] = lg[c] - m - ls;
    }
}

} // namespace

extern "C" void kernel_launch(void* const* d_in, const int* in_sizes, int n_in,
                              void* d_out, int out_size, void* d_ws, size_t ws_size,
                              hipStream_t stream)
{
    const float* src   = (const float*)d_in[0];
    const float* emb_W = (const float*)d_in[1];
    const float* emb_b = (const float*)d_in[2];
    const float* Wqkv  = (const float*)d_in[3];
    const float* bqkv  = (const float*)d_in[4];
    const float* Wo    = (const float*)d_in[5];
    const float* bo    = (const float*)d_in[6];
    const float* ln1_g = (const float*)d_in[7];
    const float* ln1_b = (const float*)d_in[8];
    const float* ln2_g = (const float*)d_in[9];
    const float* ln2_b = (const float*)d_in[10];
    const float* W1    = (const float*)d_in[11];
    const float* b1    = (const float*)d_in[12];
    const float* W2    = (const float*)d_in[13];
    const float* b2    = (const float*)d_in[14];
    const float* dec_W = (const float*)d_in[15];

    float* out   = (float*)d_out;               // [32,10]
    float* attns = out + BATCH*NCLS;            // [4,32,512,512]

    // workspace layout (~35 MB)
    char* ws = (char*)d_ws;
    __hip_bfloat16* xb16 = (__hip_bfloat16*)ws;     ws += (size_t)NTOK*EMB*2;     //  8.39 MB
    __hip_bfloat16* kbuf = (__hip_bfloat16*)ws;     ws += (size_t)NTOK*EMB*2;     //  8.39 MB
    __hip_bfloat16* vbuf = (__hip_bfloat16*)ws;     ws += (size_t)NTOK*EMB*2;     //  8.39 MB
    __hip_bfloat16* obuf = (__hip_bfloat16*)ws;     ws += (size_t)BATCH*EMB*2;
    __hip_bfloat16* wq16 = (__hip_bfloat16*)ws;     ws += (size_t)NLAYER*3*EMB*EMB*2;
    __hip_bfloat16* wo16 = (__hip_bfloat16*)ws;     ws += (size_t)NLAYER*EMB*EMB*2;
    __hip_bfloat16* w116 = (__hip_bfloat16*)ws;     ws += (size_t)NLAYER*FF*EMB*2;
    __hip_bfloat16* w216 = (__hip_bfloat16*)ws;     ws += (size_t)NLAYER*EMB*FF*2;
    float*          amall= (float*)ws;              ws += (size_t)NLAYER*BATCH*NHEADS*SEQ*4; // 2.1 MB

    // weight conversion fp32 -> bf16 (single launch)
    f2b_all<<<3072, 256, 0, stream>>>(Wqkv, Wo, W1, W2, wq16, wo16, w116, w216);

    // fused embed + pos-enc + layer-0 k|v projection
    embed_kv<<<NTOK/64, 512, 0, stream>>>(
        src, emb_W, emb_b,
        wq16 + (size_t)EMB*EMB, bqkv + EMB, bqkv + 2*EMB,
        xb16, kbuf, vbuf);

    for (int l = 0; l < NLAYER; l++) {
        const __hip_bfloat16* wql = wq16 + (size_t)l*3*EMB*EMB;
        const float* bql = bqkv + (size_t)l*3*EMB;

        // fused per-(b,h): q GEMV + scores + softmax + per-head row + o_last -> obuf
        attn_last_head<<<dim3(NHEADS, BATCH), 512, 0, stream>>>(
            xb16, wql, bql, kbuf, vbuf, obuf, amall + (size_t)l*BATCH*NHEADS*SEQ);

        // fused tail: Wo + res + LN1 + FFN1 + FFN2 + res + LN2 (+ next-layer kv)
        const bool last = (l == NLAYER-1);
        const __hip_bfloat16* wkv_next = last ? nullptr
            : wq16 + (size_t)(l+1)*3*EMB*EMB + (size_t)EMB*EMB;
        const float* bk_next = last ? nullptr : bqkv + (size_t)(l+1)*3*EMB + EMB;
        const float* bv_next = last ? nullptr : bqkv + (size_t)(l+1)*3*EMB + 2*EMB;
        layer_tail<<<NTOK/64, 512, 0, stream>>>(
            vbuf, obuf,
            wo16 + (size_t)l*EMB*EMB, bo + (size_t)l*EMB,
            ln1_g + l*EMB, ln1_b + l*EMB,
            w116 + (size_t)l*FF*EMB, b1 + (size_t)l*FF,
            w216 + (size_t)l*EMB*FF, b2 + (size_t)l*EMB,
            ln2_g + l*EMB, ln2_b + l*EMB,
            xb16,
            wkv_next, bk_next, bv_next,
            last ? nullptr : kbuf, last ? nullptr : vbuf);
    }

    {
        size_t total_f4 = (size_t)NLAYER*BATCH*SEQ*(SEQ/4);
        int blocks = (int)((total_f4 + 255)/256);
        write_attns<<<blocks, 256, 0, stream>>>(attns, amall);
    }

    decode_fused<<<BATCH, 512, 0, stream>>>(xb16, dec_W, out);
}